// Round 1
// baseline (866.462 us; speedup 1.0000x reference)
//
#include <hip/hip_runtime.h>
#include <hip/hip_bf16.h>

typedef unsigned short u16;
typedef unsigned int u32;
typedef __bf16 bf16x8 __attribute__((ext_vector_type(8)));
typedef float f32x4 __attribute__((ext_vector_type(4)));

#define S_ 2048
#define H_ 32
#define KV_ 8
#define D_ 128
#define HID_ 4096
#define KVD_ 1024
#define SINK_ 128
#define WIN_ 1024
#define POOL_ 100

__device__ __forceinline__ u16 f2bf(float f) {
  union { float f; u32 u; } v; v.f = f;
  u32 r = v.u + 0x7FFFu + ((v.u >> 16) & 1u);
  return (u16)(r >> 16);
}
__device__ __forceinline__ float bf2f(u16 h) {
  union { u32 u; float f; } v; v.u = ((u32)h) << 16;
  return v.f;
}
// async global->LDS, 16B per lane. LDS dest must be wave-uniform base; HW writes base + lane*16.
__device__ __forceinline__ void glds16(const void* g, void* l) {
  __builtin_amdgcn_global_load_lds((__attribute__((address_space(1))) void*)g,
                                   (__attribute__((address_space(3))) void*)l, 16, 0, 0);
}

// ---------------- elementwise fp32 -> bf16 (4/thread) ----------------
__global__ void k_f32_to_bf16(const float* __restrict__ x, u16* __restrict__ y, int n4) {
  int i = blockIdx.x * 256 + threadIdx.x;
  if (i >= n4) return;
  float4 v = ((const float4*)x)[i];
  union { u16 s[4]; unsigned long long ll; } o;
  o.s[0] = f2bf(v.x); o.s[1] = f2bf(v.y); o.s[2] = f2bf(v.z); o.s[3] = f2bf(v.w);
  ((unsigned long long*)y)[i] = o.ll;
}

// ---------------- W (K,N) fp32 -> Wt (N,K) bf16, 32x32 LDS tile ----------------
__global__ void k_transpose_w(const float* __restrict__ W, u16* __restrict__ Wt, int K, int N) {
  __shared__ u16 T[32][33];
  int nt = blockIdx.x, kt = blockIdx.y;
  int c = threadIdx.x & 31, r0 = threadIdx.x >> 5;
#pragma unroll
  for (int p = 0; p < 4; ++p) {
    int r = r0 + p * 8;
    T[r][c] = f2bf(W[(size_t)(kt * 32 + r) * N + nt * 32 + c]);
  }
  __syncthreads();
#pragma unroll
  for (int p = 0; p < 4; ++p) {
    int r = r0 + p * 8;
    Wt[(size_t)(nt * 32 + r) * K + kt * 32 + c] = T[c][r];
  }
}

// ---------------- v (s, kv*128) bf16 -> vt (kv, d, s) bf16 ----------------
__global__ void k_transpose_v(const u16* __restrict__ v, u16* __restrict__ vt) {
  __shared__ u16 T[32][33];
  int st = blockIdx.x, dt = blockIdx.y, kv = blockIdx.z;
  int c = threadIdx.x & 31, r0 = threadIdx.x >> 5;
#pragma unroll
  for (int p = 0; p < 4; ++p) {
    int r = r0 + p * 8;
    T[r][c] = v[(size_t)(st * 32 + r) * KVD_ + kv * D_ + dt * 32 + c];
  }
  __syncthreads();
#pragma unroll
  for (int p = 0; p < 4; ++p) {
    int r = r0 + p * 8;
    vt[(size_t)kv * D_ * S_ + (size_t)(dt * 32 + r) * S_ + st * 32 + c] = T[c][r];
  }
}

// ---------------- RoPE tables ----------------
__global__ void k_rope_table(float* __restrict__ cosT, float* __restrict__ sinT) {
  int idx = blockIdx.x * 256 + threadIdx.x;
  if (idx >= S_ * 64) return;
  int s = idx >> 6, i = idx & 63;
  float inv = powf(10000.f, -(float)i * (1.f / 64.f));
  float ang = (float)s * inv;
  cosT[idx] = cosf(ang);
  sinT[idx] = sinf(ang);
}

// ---------------- RoPE on q in-place (layout (s, h*128+d)) ----------------
__global__ void k_rope_q(u16* __restrict__ q, const float* __restrict__ cosT, const float* __restrict__ sinT) {
  int idx = blockIdx.x * 256 + threadIdx.x;
  if (idx >= S_ * H_ * 64) return;
  int i = idx & 63, h = (idx >> 6) & 31, s = idx >> 11;
  size_t base = (size_t)s * HID_ + h * D_ + i;
  float x1 = bf2f(q[base]), x2 = bf2f(q[base + 64]);
  float cs = cosT[(s << 6) + i], sn = sinT[(s << 6) + i];
  q[base] = f2bf(x1 * cs - x2 * sn);
  q[base + 64] = f2bf(x2 * cs + x1 * sn);
}

// ---------------- RoPE on k, relayout (s, kv*128) -> (kv, s, 128) ----------------
__global__ void k_rope_k(const u16* __restrict__ k, u16* __restrict__ kro,
                         const float* __restrict__ cosT, const float* __restrict__ sinT) {
  int idx = blockIdx.x * 256 + threadIdx.x;
  if (idx >= S_ * KV_ * 64) return;
  int i = idx & 63, kv = (idx >> 6) & 7, s = idx >> 9;
  float x1 = bf2f(k[(size_t)s * KVD_ + kv * D_ + i]);
  float x2 = bf2f(k[(size_t)s * KVD_ + kv * D_ + i + 64]);
  float cs = cosT[(s << 6) + i], sn = sinT[(s << 6) + i];
  size_t ob = (size_t)kv * S_ * D_ + (size_t)s * D_ + i;
  kro[ob] = f2bf(x1 * cs - x2 * sn);
  kro[ob + 64] = f2bf(x2 * cs + x1 * sn);
}

// ---------------- pooled feature: mean over (first 100 + last 100 pos) x 32 heads ----------------
__global__ void k_feat(const u16* __restrict__ q, float* __restrict__ feat) {
  int d = blockIdx.x, tid = threadIdx.x;
  float p = 0.f;
  for (int idx = tid; idx < 2 * POOL_ * H_; idx += 256) {
    int pos = idx >> 5, hh = idx & 31;
    int s = pos < POOL_ ? pos : (S_ - 2 * POOL_) + pos;
    p += bf2f(q[(size_t)s * HID_ + hh * D_ + d]);
  }
#pragma unroll
  for (int m = 1; m < 64; m <<= 1) p += __shfl_xor(p, m);
  __shared__ float red[4];
  if ((tid & 63) == 0) red[tid >> 6] = p;
  __syncthreads();
  if (tid == 0) feat[d] = (red[0] + red[1] + red[2] + red[3]) * (1.f / (2 * POOL_ * H_));
}

// ---------------- router MLP (fp32, single block) ----------------
__global__ void k_router(const float* __restrict__ feat,
                         const float* __restrict__ fe1_w, const float* __restrict__ fe1_b,
                         const float* __restrict__ fe2_w, const float* __restrict__ fe2_b,
                         const float* __restrict__ r1_w, const float* __restrict__ r1_b,
                         const float* __restrict__ r2_w, const float* __restrict__ r2_b,
                         const float* __restrict__ r3_w, const float* __restrict__ r3_b,
                         const float* __restrict__ noise, float* __restrict__ mix) {
  __shared__ float fs[128], h1[1024], h2[256], h3[512], h4[128];
  int tid = threadIdx.x;
  if (tid < 128) fs[tid] = feat[tid];
  __syncthreads();
  for (int o = tid; o < 1024; o += 256) {
    float a = fe1_b[o];
    for (int kk = 0; kk < 128; ++kk) a += fs[kk] * fe1_w[kk * 1024 + o];
    h1[o] = a / (1.f + expf(-a));
  }
  __syncthreads();
  {
    float a = fe2_b[tid];
    for (int kk = 0; kk < 1024; ++kk) a += h1[kk] * fe2_w[kk * 256 + tid];
    h2[tid] = a;
  }
  __syncthreads();
  for (int o = tid; o < 512; o += 256) {
    float a = r1_b[o];
    for (int kk = 0; kk < 256; ++kk) a += h2[kk] * r1_w[kk * 512 + o];
    h3[o] = a / (1.f + expf(-a));
  }
  __syncthreads();
  if (tid < 128) {
    float a = r2_b[tid];
    for (int kk = 0; kk < 512; ++kk) a += h3[kk] * r2_w[kk * 128 + tid];
    h4[tid] = a / (1.f + expf(-a));
  }
  __syncthreads();
  if (tid == 0) {
    float a = r3_b[0];
    for (int kk = 0; kk < 128; ++kk) a += h4[kk] * r3_w[kk];
    float u = noise[0];
    float g = -logf(-logf(u + 1e-8f) + 1e-8f);
    float zs = 1.f / (1.f + expf(-(a + g)));
    mix[0] = zs > 0.5f ? 1.f : 0.f;
  }
}

// ---------------- bf16 GEMM: C(M,N) = A(M,K) @ Bt(N,K)^T, 128x128 tile, BK=32 ----------------
template <int OUTF32>
__global__ __launch_bounds__(256) void gemm_bt(const u16* __restrict__ A, const u16* __restrict__ Bt,
                                               void* __restrict__ C, int M, int N, int K) {
  __shared__ __align__(16) u16 As[128 * 32];
  __shared__ __align__(16) u16 Bs[128 * 32];
  const int tid = threadIdx.x;
  const int w = tid >> 6, ln = tid & 63;
  const int lr = ln & 15, lk = ln >> 4;
  const int m0 = blockIdx.y * 128, n0 = blockIdx.x * 128;
  const int wr = w >> 1, wc = w & 1;
  f32x4 acc[4][4];
#pragma unroll
  for (int i = 0; i < 4; ++i)
#pragma unroll
    for (int j = 0; j < 4; ++j) acc[i][j] = (f32x4){0.f, 0.f, 0.f, 0.f};
  const int srow = ln >> 2, sseg = ln & 3;
  for (int k0 = 0; k0 < K; k0 += 32) {
    __syncthreads();
#pragma unroll
    for (int c = 0; c < 2; ++c) {
      int row = c * 64 + w * 16 + srow;
      glds16(A + (size_t)(m0 + row) * K + k0 + sseg * 8, &As[(c * 64 + w * 16) * 32]);
      glds16(Bt + (size_t)(n0 + row) * K + k0 + sseg * 8, &Bs[(c * 64 + w * 16) * 32]);
    }
    __syncthreads();
    bf16x8 af[4], bfr[4];
#pragma unroll
    for (int i = 0; i < 4; ++i) af[i] = *(const bf16x8*)&As[(wr * 64 + i * 16 + lr) * 32 + lk * 8];
#pragma unroll
    for (int i = 0; i < 4; ++i) bfr[i] = *(const bf16x8*)&Bs[(wc * 64 + i * 16 + lr) * 32 + lk * 8];
#pragma unroll
    for (int mi = 0; mi < 4; ++mi)
#pragma unroll
      for (int ni = 0; ni < 4; ++ni)
        acc[mi][ni] = __builtin_amdgcn_mfma_f32_16x16x32_bf16(af[mi], bfr[ni], acc[mi][ni], 0, 0, 0);
  }
#pragma unroll
  for (int mi = 0; mi < 4; ++mi)
#pragma unroll
    for (int ni = 0; ni < 4; ++ni)
#pragma unroll
      for (int jj = 0; jj < 4; ++jj) {
        int row = m0 + wr * 64 + mi * 16 + lk * 4 + jj;
        int col = n0 + wc * 64 + ni * 16 + lr;
        float v = acc[mi][ni][jj];
        if (OUTF32) ((float*)C)[(size_t)row * N + col] = v;
        else ((u16*)C)[(size_t)row * N + col] = f2bf(v);
      }
}

// ---------------- fused attention: 64 q-rows/block, runtime mask select via mix ----------------
__global__ __launch_bounds__(256) void k_attn(const u16* __restrict__ q, const u16* __restrict__ kr,
                                              const u16* __restrict__ vt, u16* __restrict__ o,
                                              const float* __restrict__ mixp) {
  __shared__ __align__(16) u16 Ks[32 * 128];  // (kpos, d)
  __shared__ __align__(16) u16 Vs[128 * 32];  // (d, kpos)
  __shared__ __align__(16) u16 Ps[4][16 * 32];
  const int tid = threadIdx.x, w = tid >> 6, ln = tid & 63;
  const int lr = ln & 15, lk = ln >> 4;
  const int qblk = blockIdx.x, h = blockIdx.y, kv = h >> 2;
  const bool strm = (*mixp) > 0.5f;
  const int qrow = qblk * 64 + w * 16 + lr;
  bf16x8 qf[4];
#pragma unroll
  for (int c = 0; c < 4; ++c)
    qf[c] = *(const bf16x8*)(q + (size_t)qrow * HID_ + h * D_ + c * 32 + lk * 8);
  f32x4 oacc[8];
#pragma unroll
  for (int c = 0; c < 8; ++c) oacc[c] = (f32x4){0.f, 0.f, 0.f, 0.f};
  float mrun[4], lrun[4];
#pragma unroll
  for (int j = 0; j < 4; ++j) { mrun[j] = -1e30f; lrun[j] = 0.f; }
  const u16* kbase = kr + (size_t)kv * S_ * D_;
  const u16* vbase = vt + (size_t)kv * D_ * S_;
  const int ktiles = 2 * qblk + 2;
  const int qg0 = qblk * 64 + w * 16 + lk * 4;
  const float scale = 0.08838834764831845f;
  for (int kt = 0; kt < ktiles; ++kt) {
    __syncthreads();
#pragma unroll
    for (int c = 0; c < 2; ++c) {
      glds16(kbase + (size_t)kt * 4096 + w * 1024 + c * 512 + ln * 8, &Ks[w * 1024 + c * 512]);
      int dd = c * 64 + w * 16 + (ln >> 2);
      glds16(vbase + (size_t)dd * S_ + kt * 32 + (ln & 3) * 8, &Vs[c * 2048 + w * 512]);
    }
    __syncthreads();
    f32x4 s0 = (f32x4){0.f, 0.f, 0.f, 0.f}, s1 = (f32x4){0.f, 0.f, 0.f, 0.f};
#pragma unroll
    for (int c = 0; c < 4; ++c) {
      bf16x8 kf0 = *(const bf16x8*)&Ks[lr * 128 + c * 32 + lk * 8];
      bf16x8 kf1 = *(const bf16x8*)&Ks[(16 + lr) * 128 + c * 32 + lk * 8];
      s0 = __builtin_amdgcn_mfma_f32_16x16x32_bf16(qf[c], kf0, s0, 0, 0, 0);
      s1 = __builtin_amdgcn_mfma_f32_16x16x32_bf16(qf[c], kf1, s1, 0, 0, 0);
    }
    float rmax[4];
    const int kg0 = kt * 32 + lr;
#pragma unroll
    for (int j = 0; j < 4; ++j) {
      int qi = qg0 + j;
      float v0 = s0[j] * scale, v1 = s1[j] * scale;
      bool ok0 = (kg0 <= qi) && (!strm || kg0 < SINK_ || kg0 > qi - WIN_);
      int kg1 = kg0 + 16;
      bool ok1 = (kg1 <= qi) && (!strm || kg1 < SINK_ || kg1 > qi - WIN_);
      v0 = ok0 ? v0 : -1e30f;
      v1 = ok1 ? v1 : -1e30f;
      s0[j] = v0; s1[j] = v1;
      rmax[j] = fmaxf(v0, v1);
    }
#pragma unroll
    for (int m2 = 1; m2 < 16; m2 <<= 1)
#pragma unroll
      for (int j = 0; j < 4; ++j) rmax[j] = fmaxf(rmax[j], __shfl_xor(rmax[j], m2));
    float corr[4];
#pragma unroll
    for (int j = 0; j < 4; ++j) {
      float mn = fmaxf(mrun[j], rmax[j]);
      corr[j] = __expf(mrun[j] - mn);
      mrun[j] = mn;
    }
    float rsum[4];
#pragma unroll
    for (int j = 0; j < 4; ++j) {
      float p0 = __expf(s0[j] - mrun[j]);
      float p1 = __expf(s1[j] - mrun[j]);
      s0[j] = p0; s1[j] = p1;
      rsum[j] = p0 + p1;
    }
#pragma unroll
    for (int m2 = 1; m2 < 16; m2 <<= 1)
#pragma unroll
      for (int j = 0; j < 4; ++j) rsum[j] += __shfl_xor(rsum[j], m2);
#pragma unroll
    for (int j = 0; j < 4; ++j) lrun[j] = lrun[j] * corr[j] + rsum[j];
#pragma unroll
    for (int c = 0; c < 8; ++c) {
      f32x4 t = oacc[c];
      t[0] *= corr[0]; t[1] *= corr[1]; t[2] *= corr[2]; t[3] *= corr[3];
      oacc[c] = t;
    }
#pragma unroll
    for (int j = 0; j < 4; ++j) {
      Ps[w][(lk * 4 + j) * 32 + lr] = f2bf(s0[j]);
      Ps[w][(lk * 4 + j) * 32 + 16 + lr] = f2bf(s1[j]);
    }
    bf16x8 pf = *(const bf16x8*)&Ps[w][lr * 32 + lk * 8];
#pragma unroll
    for (int c = 0; c < 8; ++c) {
      bf16x8 vf = *(const bf16x8*)&Vs[(c * 16 + lr) * 32 + lk * 8];
      oacc[c] = __builtin_amdgcn_mfma_f32_16x16x32_bf16(pf, vf, oacc[c], 0, 0, 0);
    }
  }
#pragma unroll
  for (int c = 0; c < 8; ++c)
#pragma unroll
    for (int j = 0; j < 4; ++j) {
      float ov = oacc[c][j] / lrun[j];
      o[(size_t)(qg0 + j) * HID_ + h * D_ + c * 16 + lr] = f2bf(ov);
    }
}

extern "C" void kernel_launch(void* const* d_in, const int* in_sizes, int n_in,
                              void* d_out, int out_size, void* d_ws, size_t ws_size,
                              hipStream_t stream) {
  const float* hs = (const float*)d_in[0];
  const float* Wq = (const float*)d_in[1];
  const float* Wk = (const float*)d_in[2];
  const float* Wv = (const float*)d_in[3];
  const float* Wo = (const float*)d_in[4];
  const float* fe1_w = (const float*)d_in[5];
  const float* fe1_b = (const float*)d_in[6];
  const float* fe2_w = (const float*)d_in[7];
  const float* fe2_b = (const float*)d_in[8];
  const float* r1_w = (const float*)d_in[9];
  const float* r1_b = (const float*)d_in[10];
  const float* r2_w = (const float*)d_in[11];
  const float* r2_b = (const float*)d_in[12];
  const float* r3_w = (const float*)d_in[13];
  const float* r3_b = (const float*)d_in[14];
  const float* noise = (const float*)d_in[15];

  char* ws = (char*)d_ws;
  size_t off = 0;
  auto alloc = [&](size_t b) { char* p = ws + off; off += (b + 255) & ~(size_t)255; return p; };
  u16* hsb = (u16*)alloc((size_t)S_ * HID_ * 2);
  u16* wbig = (u16*)alloc((size_t)HID_ * HID_ * 2);  // Wq^T, later reused for Wo^T
  u16* wkt = (u16*)alloc((size_t)KVD_ * HID_ * 2);
  u16* wvt = (u16*)alloc((size_t)KVD_ * HID_ * 2);
  u16* qbuf = (u16*)alloc((size_t)S_ * HID_ * 2);
  u16* kbuf = (u16*)alloc((size_t)S_ * KVD_ * 2);
  u16* krbuf = (u16*)alloc((size_t)S_ * KVD_ * 2);
  u16* vbuf = (u16*)alloc((size_t)S_ * KVD_ * 2);
  u16* vtbuf = (u16*)alloc((size_t)S_ * KVD_ * 2);
  u16* obuf = (u16*)alloc((size_t)S_ * HID_ * 2);
  float* cosT = (float*)alloc((size_t)S_ * 64 * 4);
  float* sinT = (float*)alloc((size_t)S_ * 64 * 4);
  float* feat = (float*)alloc(512);
  float* mix = (float*)alloc(256);

  k_f32_to_bf16<<<dim3(S_ * HID_ / 4 / 256), dim3(256), 0, stream>>>(hs, hsb, S_ * HID_ / 4);
  k_transpose_w<<<dim3(HID_ / 32, HID_ / 32), dim3(256), 0, stream>>>(Wq, wbig, HID_, HID_);
  k_transpose_w<<<dim3(KVD_ / 32, HID_ / 32), dim3(256), 0, stream>>>(Wk, wkt, HID_, KVD_);
  k_transpose_w<<<dim3(KVD_ / 32, HID_ / 32), dim3(256), 0, stream>>>(Wv, wvt, HID_, KVD_);
  k_rope_table<<<dim3(S_ * 64 / 256), dim3(256), 0, stream>>>(cosT, sinT);

  gemm_bt<0><<<dim3(HID_ / 128, S_ / 128), dim3(256), 0, stream>>>(hsb, wbig, (void*)qbuf, S_, HID_, HID_);
  gemm_bt<0><<<dim3(KVD_ / 128, S_ / 128), dim3(256), 0, stream>>>(hsb, wkt, (void*)kbuf, S_, KVD_, HID_);
  gemm_bt<0><<<dim3(KVD_ / 128, S_ / 128), dim3(256), 0, stream>>>(hsb, wvt, (void*)vbuf, S_, KVD_, HID_);

  k_rope_q<<<dim3(S_ * H_ * 64 / 256), dim3(256), 0, stream>>>(qbuf, cosT, sinT);
  k_rope_k<<<dim3(S_ * KV_ * 64 / 256), dim3(256), 0, stream>>>(kbuf, krbuf, cosT, sinT);
  k_transpose_v<<<dim3(S_ / 32, D_ / 32, KV_), dim3(256), 0, stream>>>(vbuf, vtbuf);

  k_feat<<<dim3(D_), dim3(256), 0, stream>>>(qbuf, feat);
  k_router<<<dim3(1), dim3(256), 0, stream>>>(feat, fe1_w, fe1_b, fe2_w, fe2_b,
                                              r1_w, r1_b, r2_w, r2_b, r3_w, r3_b, noise, mix);

  k_attn<<<dim3(S_ / 64, H_), dim3(256), 0, stream>>>(qbuf, krbuf, vtbuf, obuf, mix);

  k_transpose_w<<<dim3(HID_ / 32, HID_ / 32), dim3(256), 0, stream>>>(Wo, wbig, HID_, HID_);
  gemm_bt<1><<<dim3(HID_ / 128, S_ / 128), dim3(256), 0, stream>>>(obuf, wbig, d_out, S_, HID_, HID_);
}

// Round 2
// 570.455 us; speedup vs baseline: 1.5189x; 1.5189x over previous
//
#include <hip/hip_runtime.h>
#include <hip/hip_bf16.h>

typedef unsigned short u16;
typedef unsigned int u32;
typedef __bf16 bf16x8 __attribute__((ext_vector_type(8)));
typedef float f32x4 __attribute__((ext_vector_type(4)));

#define S_ 2048
#define H_ 32
#define KV_ 8
#define D_ 128
#define HID_ 4096
#define KVD_ 1024
#define SINK_ 128
#define WIN_ 1024
#define POOL_ 100
#define KVB 64

__device__ __forceinline__ u16 f2bf(float f) {
  union { float f; u32 u; } v; v.f = f;
  u32 r = v.u + 0x7FFFu + ((v.u >> 16) & 1u);
  return (u16)(r >> 16);
}
__device__ __forceinline__ float bf2f(u16 h) {
  union { u32 u; float f; } v; v.u = ((u32)h) << 16;
  return v.f;
}
// async global->LDS, 16B per lane. LDS dest is wave-uniform base; HW writes base + lane*16.
__device__ __forceinline__ void glds16(const void* g, void* l) {
  __builtin_amdgcn_global_load_lds((__attribute__((address_space(1))) void*)g,
                                   (__attribute__((address_space(3))) void*)l, 16, 0, 0);
}

// ---------------- elementwise fp32 -> bf16 (4/thread) ----------------
__global__ void k_f32_to_bf16(const float* __restrict__ x, u16* __restrict__ y, int n4) {
  int i = blockIdx.x * 256 + threadIdx.x;
  if (i >= n4) return;
  float4 v = ((const float4*)x)[i];
  union { u16 s[4]; unsigned long long ll; } o;
  o.s[0] = f2bf(v.x); o.s[1] = f2bf(v.y); o.s[2] = f2bf(v.z); o.s[3] = f2bf(v.w);
  ((unsigned long long*)y)[i] = o.ll;
}

// ---------------- W (K,N) fp32 -> Wt (N,K) bf16, 32x32 LDS tile ----------------
__global__ void k_transpose_w(const float* __restrict__ W, u16* __restrict__ Wt, int K, int N) {
  __shared__ u16 T[32][33];
  int nt = blockIdx.x, kt = blockIdx.y;
  int c = threadIdx.x & 31, r0 = threadIdx.x >> 5;
#pragma unroll
  for (int p = 0; p < 4; ++p) {
    int r = r0 + p * 8;
    T[r][c] = f2bf(W[(size_t)(kt * 32 + r) * N + nt * 32 + c]);
  }
  __syncthreads();
#pragma unroll
  for (int p = 0; p < 4; ++p) {
    int r = r0 + p * 8;
    Wt[(size_t)(nt * 32 + r) * K + kt * 32 + c] = T[c][r];
  }
}

// ---------------- v (s, 2048: cols 1024.. are v) bf16 -> vt (kv, d, s) bf16 ----------------
__global__ void k_transpose_v(const u16* __restrict__ v, u16* __restrict__ vt) {
  __shared__ u16 T[32][33];
  int st = blockIdx.x, dt = blockIdx.y, kv = blockIdx.z;
  int c = threadIdx.x & 31, r0 = threadIdx.x >> 5;
#pragma unroll
  for (int p = 0; p < 4; ++p) {
    int r = r0 + p * 8;
    T[r][c] = v[(size_t)(st * 32 + r) * (2 * KVD_) + KVD_ + kv * D_ + dt * 32 + c];
  }
  __syncthreads();
#pragma unroll
  for (int p = 0; p < 4; ++p) {
    int r = r0 + p * 8;
    vt[(size_t)kv * D_ * S_ + (size_t)(dt * 32 + r) * S_ + st * 32 + c] = T[c][r];
  }
}

// ---------------- RoPE tables ----------------
__global__ void k_rope_table(float* __restrict__ cosT, float* __restrict__ sinT) {
  int idx = blockIdx.x * 256 + threadIdx.x;
  if (idx >= S_ * 64) return;
  int s = idx >> 6, i = idx & 63;
  float inv = powf(10000.f, -(float)i * (1.f / 64.f));
  float ang = (float)s * inv;
  cosT[idx] = cosf(ang);
  sinT[idx] = sinf(ang);
}

// ---------------- RoPE on q in-place (layout (s, h*128+d)) ----------------
__global__ void k_rope_q(u16* __restrict__ q, const float* __restrict__ cosT, const float* __restrict__ sinT) {
  int idx = blockIdx.x * 256 + threadIdx.x;
  if (idx >= S_ * H_ * 64) return;
  int i = idx & 63, h = (idx >> 6) & 31, s = idx >> 11;
  size_t base = (size_t)s * HID_ + h * D_ + i;
  float x1 = bf2f(q[base]), x2 = bf2f(q[base + 64]);
  float cs = cosT[(s << 6) + i], sn = sinT[(s << 6) + i];
  q[base] = f2bf(x1 * cs - x2 * sn);
  q[base + 64] = f2bf(x2 * cs + x1 * sn);
}

// ---------------- RoPE on k (from fused kv buf, row stride 2048), relayout -> (kv, s, 128) ----------------
__global__ void k_rope_k(const u16* __restrict__ k, u16* __restrict__ kro,
                         const float* __restrict__ cosT, const float* __restrict__ sinT) {
  int idx = blockIdx.x * 256 + threadIdx.x;
  if (idx >= S_ * KV_ * 64) return;
  int i = idx & 63, kv = (idx >> 6) & 7, s = idx >> 9;
  float x1 = bf2f(k[(size_t)s * (2 * KVD_) + kv * D_ + i]);
  float x2 = bf2f(k[(size_t)s * (2 * KVD_) + kv * D_ + i + 64]);
  float cs = cosT[(s << 6) + i], sn = sinT[(s << 6) + i];
  size_t ob = (size_t)kv * S_ * D_ + (size_t)s * D_ + i;
  kro[ob] = f2bf(x1 * cs - x2 * sn);
  kro[ob + 64] = f2bf(x2 * cs + x1 * sn);
}

// ---------------- pooled feature ----------------
__global__ void k_feat(const u16* __restrict__ q, float* __restrict__ feat) {
  int d = blockIdx.x, tid = threadIdx.x;
  float p = 0.f;
  for (int idx = tid; idx < 2 * POOL_ * H_; idx += 256) {
    int pos = idx >> 5, hh = idx & 31;
    int s = pos < POOL_ ? pos : (S_ - 2 * POOL_) + pos;
    p += bf2f(q[(size_t)s * HID_ + hh * D_ + d]);
  }
#pragma unroll
  for (int m = 1; m < 64; m <<= 1) p += __shfl_xor(p, m);
  __shared__ float red[4];
  if ((tid & 63) == 0) red[tid >> 6] = p;
  __syncthreads();
  if (tid == 0) feat[d] = (red[0] + red[1] + red[2] + red[3]) * (1.f / (2 * POOL_ * H_));
}

// ---------------- router MLP (fp32, single block) ----------------
__global__ void k_router(const float* __restrict__ feat,
                         const float* __restrict__ fe1_w, const float* __restrict__ fe1_b,
                         const float* __restrict__ fe2_w, const float* __restrict__ fe2_b,
                         const float* __restrict__ r1_w, const float* __restrict__ r1_b,
                         const float* __restrict__ r2_w, const float* __restrict__ r2_b,
                         const float* __restrict__ r3_w, const float* __restrict__ r3_b,
                         const float* __restrict__ noise, float* __restrict__ mix) {
  __shared__ float fs[128], h1[1024], h2[256], h3[512], h4[128];
  int tid = threadIdx.x;
  if (tid < 128) fs[tid] = feat[tid];
  __syncthreads();
  for (int o = tid; o < 1024; o += 256) {
    float a = fe1_b[o];
    for (int kk = 0; kk < 128; ++kk) a += fs[kk] * fe1_w[kk * 1024 + o];
    h1[o] = a / (1.f + expf(-a));
  }
  __syncthreads();
  {
    float a = fe2_b[tid];
    for (int kk = 0; kk < 1024; ++kk) a += h1[kk] * fe2_w[kk * 256 + tid];
    h2[tid] = a;
  }
  __syncthreads();
  for (int o = tid; o < 512; o += 256) {
    float a = r1_b[o];
    for (int kk = 0; kk < 256; ++kk) a += h2[kk] * r1_w[kk * 512 + o];
    h3[o] = a / (1.f + expf(-a));
  }
  __syncthreads();
  if (tid < 128) {
    float a = r2_b[tid];
    for (int kk = 0; kk < 512; ++kk) a += h3[kk] * r2_w[kk * 128 + tid];
    h4[tid] = a / (1.f + expf(-a));
  }
  __syncthreads();
  if (tid == 0) {
    float a = r3_b[0];
    for (int kk = 0; kk < 128; ++kk) a += h4[kk] * r3_w[kk];
    float u = noise[0];
    float g = -logf(-logf(u + 1e-8f) + 1e-8f);
    float zs = 1.f / (1.f + expf(-(a + g)));
    mix[0] = zs > 0.5f ? 1.f : 0.f;
  }
}

// ---------------- bf16 GEMM: C(M,N) = A(M,K) @ Bt(N,K)^T, 128x128 tile, BK=32 ----------------
template <int OUTF32>
__global__ __launch_bounds__(256) void gemm_bt(const u16* __restrict__ A, const u16* __restrict__ Bt,
                                               void* __restrict__ C, int M, int N, int K) {
  __shared__ __align__(16) u16 As[128 * 32];
  __shared__ __align__(16) u16 Bs[128 * 32];
  const int tid = threadIdx.x;
  const int w = tid >> 6, ln = tid & 63;
  const int lr = ln & 15, lk = ln >> 4;
  const int m0 = blockIdx.y * 128, n0 = blockIdx.x * 128;
  const int wr = w >> 1, wc = w & 1;
  f32x4 acc[4][4];
#pragma unroll
  for (int i = 0; i < 4; ++i)
#pragma unroll
    for (int j = 0; j < 4; ++j) acc[i][j] = (f32x4){0.f, 0.f, 0.f, 0.f};
  const int srow = ln >> 2, sseg = ln & 3;
  for (int k0 = 0; k0 < K; k0 += 32) {
    __syncthreads();
#pragma unroll
    for (int c = 0; c < 2; ++c) {
      int row = c * 64 + w * 16 + srow;
      glds16(A + (size_t)(m0 + row) * K + k0 + sseg * 8, &As[(c * 64 + w * 16) * 32]);
      glds16(Bt + (size_t)(n0 + row) * K + k0 + sseg * 8, &Bs[(c * 64 + w * 16) * 32]);
    }
    __syncthreads();
    bf16x8 af[4], bfr[4];
#pragma unroll
    for (int i = 0; i < 4; ++i) af[i] = *(const bf16x8*)&As[(wr * 64 + i * 16 + lr) * 32 + lk * 8];
#pragma unroll
    for (int i = 0; i < 4; ++i) bfr[i] = *(const bf16x8*)&Bs[(wc * 64 + i * 16 + lr) * 32 + lk * 8];
#pragma unroll
    for (int mi = 0; mi < 4; ++mi)
#pragma unroll
      for (int ni = 0; ni < 4; ++ni)
        acc[mi][ni] = __builtin_amdgcn_mfma_f32_16x16x32_bf16(af[mi], bfr[ni], acc[mi][ni], 0, 0, 0);
  }
#pragma unroll
  for (int mi = 0; mi < 4; ++mi)
#pragma unroll
    for (int ni = 0; ni < 4; ++ni)
#pragma unroll
      for (int jj = 0; jj < 4; ++jj) {
        int row = m0 + wr * 64 + mi * 16 + lk * 4 + jj;
        int col = n0 + wc * 64 + ni * 16 + lr;
        float v = acc[mi][ni][jj];
        if (OUTF32) ((float*)C)[(size_t)row * N + col] = v;
        else ((u16*)C)[(size_t)row * N + col] = f2bf(v);
      }
}

// ---------------- fused attention v2: 64 q-rows/block, KVB=64, XOR-swizzled LDS ----------------
// Swizzle rule (16B blocks): LDS slot (row, c16) holds global col16 (c16 ^ (row&7)).
// Staged via pre-swizzled GLOBAL source + linear LDS dest (glds16); reads XOR the col16.
__global__ __launch_bounds__(256) void k_attn(const u16* __restrict__ q, const u16* __restrict__ kr,
                                              const u16* __restrict__ vt, u16* __restrict__ o,
                                              const float* __restrict__ mixp) {
  __shared__ __align__(16) u16 Ks[KVB * 128];      // (kpos, d) swizzled
  __shared__ __align__(16) u16 Vs[128 * KVB];      // (d, kpos) swizzled
  __shared__ __align__(16) u16 Ps[4][16 * KVB];    // per-wave (q, kpos) swizzled
  const int tid = threadIdx.x, w = tid >> 6, ln = tid & 63;
  const int lr = ln & 15, lk = ln >> 4;
  const int bid = blockIdx.x;
  const int qblk = (S_ / 64 - 1) - (bid >> 5);     // longest blocks dispatch first
  const int h = bid & 31, kv = h >> 2;
  const bool strm = (*mixp) > 0.5f;
  const int q0 = qblk * 64;
  const int qrow = q0 + w * 16 + lr;
  bf16x8 qf[4];
#pragma unroll
  for (int c = 0; c < 4; ++c)
    qf[c] = *(const bf16x8*)(q + (size_t)qrow * HID_ + h * D_ + c * 32 + lk * 8);
  f32x4 oacc[8];
#pragma unroll
  for (int c = 0; c < 8; ++c) oacc[c] = (f32x4){0.f, 0.f, 0.f, 0.f};
  float mrun[4], lrun[4];
#pragma unroll
  for (int j = 0; j < 4; ++j) { mrun[j] = -1e30f; lrun[j] = 0.f; }
  const u16* kbase = kr + (size_t)kv * S_ * D_;
  const u16* vbase = vt + (size_t)kv * D_ * S_;
  const int qg0 = q0 + w * 16 + lk * 4;            // q row of D-fragment (col=lr)
  const float scale = 0.08838834764831845f;
  const int ntiles = qblk + 1;
  for (int kt = 0; kt < ntiles; ++kt) {
    const int kb0 = kt * KVB;
    // streaming: tile fully masked (past sink, fully outside window for every q in block)
    if (strm && kb0 >= SINK_ && kb0 + KVB - 1 + WIN_ <= q0) continue;
    __syncthreads();
    // stage K tile: 64 rows x 256B. wave w, chunk c stages rows c*16+w*4 .. +4 (1KB linear)
#pragma unroll
    for (int c = 0; c < 4; ++c) {
      int r0 = c * 16 + w * 4;
      int rg = r0 + (ln >> 4);
      int cg = (ln & 15) ^ (rg & 7);
      glds16(kbase + (size_t)(kb0 + rg) * D_ + cg * 8, &Ks[r0 * 128]);
    }
    // stage V tile: 128 d-rows x 128B. wave w, chunk c stages rows c*32+w*8 .. +8
#pragma unroll
    for (int c = 0; c < 4; ++c) {
      int r0 = c * 32 + w * 8;
      int rg = r0 + (ln >> 3);
      int cg = (ln & 7) ^ (rg & 7);
      glds16(vbase + (size_t)rg * S_ + kb0 + cg * 8, &Vs[r0 * KVB]);
    }
    __syncthreads();
    // QK^T: 4 groups of 16 kpos
    f32x4 sg[4];
#pragma unroll
    for (int g = 0; g < 4; ++g) sg[g] = (f32x4){0.f, 0.f, 0.f, 0.f};
#pragma unroll
    for (int g = 0; g < 4; ++g) {
      int krow = g * 16 + lr;
      int sw = krow & 7;
#pragma unroll
      for (int c = 0; c < 4; ++c) {
        bf16x8 kf = *(const bf16x8*)&Ks[krow * 128 + (((c * 4 + lk) ^ sw) * 8)];
        sg[g] = __builtin_amdgcn_mfma_f32_16x16x32_bf16(qf[c], kf, sg[g], 0, 0, 0);
      }
    }
    // mask+scale (skip compare VALU on tiles that are provably unmasked)
    const bool lastt = (kt == qblk);
    const bool needm = lastt ||
        (strm && !(kb0 + KVB <= SINK_ || kb0 >= q0 + 64 - WIN_));
    if (needm) {
#pragma unroll
      for (int g = 0; g < 4; ++g) {
        int kg = kb0 + g * 16 + lr;
#pragma unroll
        for (int j = 0; j < 4; ++j) {
          int qi = qg0 + j;
          float v = sg[g][j] * scale;
          bool ok = (kg <= qi) && (!strm || kg < SINK_ || kg > qi - WIN_);
          sg[g][j] = ok ? v : -1e30f;
        }
      }
    } else {
#pragma unroll
      for (int g = 0; g < 4; ++g)
#pragma unroll
        for (int j = 0; j < 4; ++j) sg[g][j] *= scale;
    }
    // online softmax
    float rmax[4];
#pragma unroll
    for (int j = 0; j < 4; ++j)
      rmax[j] = fmaxf(fmaxf(sg[0][j], sg[1][j]), fmaxf(sg[2][j], sg[3][j]));
#pragma unroll
    for (int m2 = 1; m2 < 16; m2 <<= 1)
#pragma unroll
      for (int j = 0; j < 4; ++j) rmax[j] = fmaxf(rmax[j], __shfl_xor(rmax[j], m2));
    float corr[4];
#pragma unroll
    for (int j = 0; j < 4; ++j) {
      float mn = fmaxf(mrun[j], rmax[j]);
      corr[j] = __expf(mrun[j] - mn);
      mrun[j] = mn;
    }
    float rsum[4] = {0.f, 0.f, 0.f, 0.f};
#pragma unroll
    for (int g = 0; g < 4; ++g)
#pragma unroll
      for (int j = 0; j < 4; ++j) {
        float p = __expf(sg[g][j] - mrun[j]);
        sg[g][j] = p;
        rsum[j] += p;
      }
#pragma unroll
    for (int m2 = 1; m2 < 16; m2 <<= 1)
#pragma unroll
      for (int j = 0; j < 4; ++j) rsum[j] += __shfl_xor(rsum[j], m2);
#pragma unroll
    for (int j = 0; j < 4; ++j) lrun[j] = lrun[j] * corr[j] + rsum[j];
#pragma unroll
    for (int c = 0; c < 8; ++c) {
      f32x4 t = oacc[c];
      t[0] *= corr[0]; t[1] *= corr[1]; t[2] *= corr[2]; t[3] *= corr[3];
      oacc[c] = t;
    }
    // P -> LDS (swizzled scalar writes; ~2-way conflicts = free)
#pragma unroll
    for (int g = 0; g < 4; ++g) {
      int col = g * 16 + lr;
      int c16 = col >> 3;
#pragma unroll
      for (int j = 0; j < 4; ++j) {
        int row = lk * 4 + j;
        Ps[w][row * KVB + ((c16 ^ (row & 7)) * 8) + (col & 7)] = f2bf(sg[g][j]);
      }
    }
    // PV: O[q][d] += P[q][k] * V[d][k]
#pragma unroll
    for (int half = 0; half < 2; ++half) {
      bf16x8 pf = *(const bf16x8*)&Ps[w][lr * KVB + (((half * 4 + lk) ^ (lr & 7)) * 8)];
#pragma unroll
      for (int cc = 0; cc < 8; ++cc) {
        int vrow = cc * 16 + lr;
        bf16x8 vf = *(const bf16x8*)&Vs[vrow * KVB + (((half * 4 + lk) ^ (vrow & 7)) * 8)];
        oacc[cc] = __builtin_amdgcn_mfma_f32_16x16x32_bf16(pf, vf, oacc[cc], 0, 0, 0);
      }
    }
  }
#pragma unroll
  for (int cc = 0; cc < 8; ++cc)
#pragma unroll
    for (int j = 0; j < 4; ++j) {
      float ov = oacc[cc][j] / lrun[j];
      o[(size_t)(qg0 + j) * HID_ + h * D_ + cc * 16 + lr] = f2bf(ov);
    }
}

extern "C" void kernel_launch(void* const* d_in, const int* in_sizes, int n_in,
                              void* d_out, int out_size, void* d_ws, size_t ws_size,
                              hipStream_t stream) {
  const float* hs = (const float*)d_in[0];
  const float* Wq = (const float*)d_in[1];
  const float* Wk = (const float*)d_in[2];
  const float* Wv = (const float*)d_in[3];
  const float* Wo = (const float*)d_in[4];
  const float* fe1_w = (const float*)d_in[5];
  const float* fe1_b = (const float*)d_in[6];
  const float* fe2_w = (const float*)d_in[7];
  const float* fe2_b = (const float*)d_in[8];
  const float* r1_w = (const float*)d_in[9];
  const float* r1_b = (const float*)d_in[10];
  const float* r2_w = (const float*)d_in[11];
  const float* r2_b = (const float*)d_in[12];
  const float* r3_w = (const float*)d_in[13];
  const float* r3_b = (const float*)d_in[14];
  const float* noise = (const float*)d_in[15];

  char* ws = (char*)d_ws;
  size_t off = 0;
  auto alloc = [&](size_t b) { char* p = ws + off; off += (b + 255) & ~(size_t)255; return p; };
  u16* hsb = (u16*)alloc((size_t)S_ * HID_ * 2);
  u16* wbig = (u16*)alloc((size_t)HID_ * HID_ * 2);   // Wq^T, later reused for Wo^T
  u16* wkt = (u16*)alloc((size_t)KVD_ * HID_ * 2);    // wkt+wvt contiguous -> fused KV GEMM
  u16* wvt = (u16*)alloc((size_t)KVD_ * HID_ * 2);
  u16* qbuf = (u16*)alloc((size_t)S_ * HID_ * 2);
  u16* kvbuf = (u16*)alloc((size_t)S_ * 2 * KVD_ * 2);
  u16* krbuf = (u16*)alloc((size_t)S_ * KVD_ * 2);
  u16* vtbuf = (u16*)alloc((size_t)S_ * KVD_ * 2);
  u16* obuf = (u16*)alloc((size_t)S_ * HID_ * 2);
  float* cosT = (float*)alloc((size_t)S_ * 64 * 4);
  float* sinT = (float*)alloc((size_t)S_ * 64 * 4);
  float* feat = (float*)alloc(512);
  float* mix = (float*)alloc(256);
  (void)wvt;

  k_f32_to_bf16<<<dim3(S_ * HID_ / 4 / 256), dim3(256), 0, stream>>>(hs, hsb, S_ * HID_ / 4);
  k_transpose_w<<<dim3(HID_ / 32, HID_ / 32), dim3(256), 0, stream>>>(Wq, wbig, HID_, HID_);
  k_transpose_w<<<dim3(KVD_ / 32, HID_ / 32), dim3(256), 0, stream>>>(Wk, wkt, HID_, KVD_);
  k_transpose_w<<<dim3(KVD_ / 32, HID_ / 32), dim3(256), 0, stream>>>(Wv, wvt, HID_, KVD_);
  k_rope_table<<<dim3(S_ * 64 / 256), dim3(256), 0, stream>>>(cosT, sinT);

  gemm_bt<0><<<dim3(HID_ / 128, S_ / 128), dim3(256), 0, stream>>>(hsb, wbig, (void*)qbuf, S_, HID_, HID_);
  // fused K+V GEMM: Bt = [Wk^T; Wv^T] contiguous (N=2048)
  gemm_bt<0><<<dim3(2 * KVD_ / 128, S_ / 128), dim3(256), 0, stream>>>(hsb, wkt, (void*)kvbuf, S_, 2 * KVD_, HID_);

  k_rope_q<<<dim3(S_ * H_ * 64 / 256), dim3(256), 0, stream>>>(qbuf, cosT, sinT);
  k_rope_k<<<dim3(S_ * KV_ * 64 / 256), dim3(256), 0, stream>>>(kvbuf, krbuf, cosT, sinT);
  k_transpose_v<<<dim3(S_ / 32, D_ / 32, KV_), dim3(256), 0, stream>>>(kvbuf, vtbuf);

  k_feat<<<dim3(D_), dim3(256), 0, stream>>>(qbuf, feat);
  k_router<<<dim3(1), dim3(256), 0, stream>>>(feat, fe1_w, fe1_b, fe2_w, fe2_b,
                                              r1_w, r1_b, r2_w, r2_b, r3_w, r3_b, noise, mix);

  k_attn<<<dim3((S_ / 64) * H_), dim3(256), 0, stream>>>(qbuf, krbuf, vtbuf, obuf, mix);

  k_transpose_w<<<dim3(HID_ / 32, HID_ / 32), dim3(256), 0, stream>>>(Wo, wbig, HID_, HID_);
  gemm_bt<1><<<dim3(HID_ / 128, S_ / 128), dim3(256), 0, stream>>>(obuf, wbig, d_out, S_, HID_, HID_);
}

// Round 3
// 522.591 us; speedup vs baseline: 1.6580x; 1.0916x over previous
//
#include <hip/hip_runtime.h>
#include <hip/hip_bf16.h>

typedef unsigned short u16;
typedef unsigned int u32;
typedef __bf16 bf16x8 __attribute__((ext_vector_type(8)));
typedef float f32x4 __attribute__((ext_vector_type(4)));

#define S_ 2048
#define H_ 32
#define KV_ 8
#define D_ 128
#define HID_ 4096
#define KVD_ 1024
#define QKVN 6144
#define SINK_ 128
#define WIN_ 1024
#define POOL_ 100
#define KVB 64

__device__ __forceinline__ u16 f2bf(float f) {
  union { float f; u32 u; } v; v.f = f;
  u32 r = v.u + 0x7FFFu + ((v.u >> 16) & 1u);
  return (u16)(r >> 16);
}
__device__ __forceinline__ float bf2f(u16 h) {
  union { u32 u; float f; } v; v.u = ((u32)h) << 16;
  return v.f;
}
// async global->LDS, 16B per lane. LDS dest is wave-uniform base; HW writes base + lane*16.
__device__ __forceinline__ void glds16(const void* g, void* l) {
  __builtin_amdgcn_global_load_lds((__attribute__((address_space(1))) void*)g,
                                   (__attribute__((address_space(3))) void*)l, 16, 0, 0);
}

// ---------------- elementwise fp32 -> bf16 (4/thread) ----------------
__global__ void k_f32_to_bf16(const float* __restrict__ x, u16* __restrict__ y, int n4) {
  int i = blockIdx.x * 256 + threadIdx.x;
  if (i >= n4) return;
  float4 v = ((const float4*)x)[i];
  union { u16 s[4]; unsigned long long ll; } o;
  o.s[0] = f2bf(v.x); o.s[1] = f2bf(v.y); o.s[2] = f2bf(v.z); o.s[3] = f2bf(v.w);
  ((unsigned long long*)y)[i] = o.ll;
}

// ---------------- W (K,N) fp32 -> Wt (N,K) bf16, 32x32 LDS tile ----------------
__global__ void k_transpose_w(const float* __restrict__ W, u16* __restrict__ Wt, int K, int N) {
  __shared__ u16 T[32][33];
  int nt = blockIdx.x, kt = blockIdx.y;
  int c = threadIdx.x & 31, r0 = threadIdx.x >> 5;
#pragma unroll
  for (int p = 0; p < 4; ++p) {
    int r = r0 + p * 8;
    T[r][c] = f2bf(W[(size_t)(kt * 32 + r) * N + nt * 32 + c]);
  }
  __syncthreads();
#pragma unroll
  for (int p = 0; p < 4; ++p) {
    int r = r0 + p * 8;
    Wt[(size_t)(nt * 32 + r) * K + kt * 32 + c] = T[c][r];
  }
}

// ---------------- v (cols 5120.. of qkv buf) bf16 -> vt (kv, d, s) bf16 ----------------
__global__ void k_transpose_v(const u16* __restrict__ v, u16* __restrict__ vt) {
  __shared__ u16 T[32][33];
  int st = blockIdx.x, dt = blockIdx.y, kv = blockIdx.z;
  int c = threadIdx.x & 31, r0 = threadIdx.x >> 5;
#pragma unroll
  for (int p = 0; p < 4; ++p) {
    int r = r0 + p * 8;
    T[r][c] = v[(size_t)(st * 32 + r) * QKVN + 5120 + kv * D_ + dt * 32 + c];
  }
  __syncthreads();
#pragma unroll
  for (int p = 0; p < 4; ++p) {
    int r = r0 + p * 8;
    vt[(size_t)kv * D_ * S_ + (size_t)(dt * 32 + r) * S_ + st * 32 + c] = T[c][r];
  }
}

// ---------------- RoPE tables ----------------
__global__ void k_rope_table(float* __restrict__ cosT, float* __restrict__ sinT) {
  int idx = blockIdx.x * 256 + threadIdx.x;
  if (idx >= S_ * 64) return;
  int s = idx >> 6, i = idx & 63;
  float inv = powf(10000.f, -(float)i * (1.f / 64.f));
  float ang = (float)s * inv;
  cosT[idx] = cosf(ang);
  sinT[idx] = sinf(ang);
}

// ---------------- RoPE on q in-place (qkv buf, row stride QKVN) ----------------
__global__ void k_rope_q(u16* __restrict__ q, const float* __restrict__ cosT, const float* __restrict__ sinT) {
  int idx = blockIdx.x * 256 + threadIdx.x;
  if (idx >= S_ * H_ * 64) return;
  int i = idx & 63, h = (idx >> 6) & 31, s = idx >> 11;
  size_t base = (size_t)s * QKVN + h * D_ + i;
  float x1 = bf2f(q[base]), x2 = bf2f(q[base + 64]);
  float cs = cosT[(s << 6) + i], sn = sinT[(s << 6) + i];
  q[base] = f2bf(x1 * cs - x2 * sn);
  q[base + 64] = f2bf(x2 * cs + x1 * sn);
}

// ---------------- RoPE on k (qkv buf cols 4096..), relayout -> (kv, s, 128) ----------------
__global__ void k_rope_k(const u16* __restrict__ k, u16* __restrict__ kro,
                         const float* __restrict__ cosT, const float* __restrict__ sinT) {
  int idx = blockIdx.x * 256 + threadIdx.x;
  if (idx >= S_ * KV_ * 64) return;
  int i = idx & 63, kv = (idx >> 6) & 7, s = idx >> 9;
  float x1 = bf2f(k[(size_t)s * QKVN + 4096 + kv * D_ + i]);
  float x2 = bf2f(k[(size_t)s * QKVN + 4096 + kv * D_ + i + 64]);
  float cs = cosT[(s << 6) + i], sn = sinT[(s << 6) + i];
  size_t ob = (size_t)kv * S_ * D_ + (size_t)s * D_ + i;
  kro[ob] = f2bf(x1 * cs - x2 * sn);
  kro[ob + 64] = f2bf(x2 * cs + x1 * sn);
}

// ---------------- pooled feature ----------------
__global__ void k_feat(const u16* __restrict__ q, float* __restrict__ feat) {
  int d = blockIdx.x, tid = threadIdx.x;
  float p = 0.f;
  for (int idx = tid; idx < 2 * POOL_ * H_; idx += 256) {
    int pos = idx >> 5, hh = idx & 31;
    int s = pos < POOL_ ? pos : (S_ - 2 * POOL_) + pos;
    p += bf2f(q[(size_t)s * QKVN + hh * D_ + d]);
  }
#pragma unroll
  for (int m = 1; m < 64; m <<= 1) p += __shfl_xor(p, m);
  __shared__ float red[4];
  if ((tid & 63) == 0) red[tid >> 6] = p;
  __syncthreads();
  if (tid == 0) feat[d] = (red[0] + red[1] + red[2] + red[3]) * (1.f / (2 * POOL_ * H_));
}

// ---------------- router MLP (fp32, single block) ----------------
__global__ void k_router(const float* __restrict__ feat,
                         const float* __restrict__ fe1_w, const float* __restrict__ fe1_b,
                         const float* __restrict__ fe2_w, const float* __restrict__ fe2_b,
                         const float* __restrict__ r1_w, const float* __restrict__ r1_b,
                         const float* __restrict__ r2_w, const float* __restrict__ r2_b,
                         const float* __restrict__ r3_w, const float* __restrict__ r3_b,
                         const float* __restrict__ noise, float* __restrict__ mix) {
  __shared__ float fs[128], h1[1024], h2[256], h3[512], h4[128];
  int tid = threadIdx.x;
  if (tid < 128) fs[tid] = feat[tid];
  __syncthreads();
  for (int o = tid; o < 1024; o += 256) {
    float a = fe1_b[o];
    for (int kk = 0; kk < 128; ++kk) a += fs[kk] * fe1_w[kk * 1024 + o];
    h1[o] = a / (1.f + expf(-a));
  }
  __syncthreads();
  {
    float a = fe2_b[tid];
    for (int kk = 0; kk < 1024; ++kk) a += h1[kk] * fe2_w[kk * 256 + tid];
    h2[tid] = a;
  }
  __syncthreads();
  for (int o = tid; o < 512; o += 256) {
    float a = r1_b[o];
    for (int kk = 0; kk < 256; ++kk) a += h2[kk] * r1_w[kk * 512 + o];
    h3[o] = a / (1.f + expf(-a));
  }
  __syncthreads();
  if (tid < 128) {
    float a = r2_b[tid];
    for (int kk = 0; kk < 512; ++kk) a += h3[kk] * r2_w[kk * 128 + tid];
    h4[tid] = a / (1.f + expf(-a));
  }
  __syncthreads();
  if (tid == 0) {
    float a = r3_b[0];
    for (int kk = 0; kk < 128; ++kk) a += h4[kk] * r3_w[kk];
    float u = noise[0];
    float g = -logf(-logf(u + 1e-8f) + 1e-8f);
    float zs = 1.f / (1.f + expf(-(a + g)));
    mix[0] = zs > 0.5f ? 1.f : 0.f;
  }
}

// ============ 256x256 GEMM, BK=32, 4-buffer deep pipeline, counted vmcnt ============
// C(M,N) = A(M,K) @ Bt(N,K)^T. 8 waves (2Mx4N), per-wave 128x64 out.
// LDS: 4 bufs x (A 256x32 + B 256x32) bf16 = 128 KiB. Swizzle: 16B cell
// (row, c16) holds global chunk c16^(row&3) -- conflict-free frag reads,
// staged both-sides (pre-swizzled global source, linear glds16 dest).
#define GBUF (16384)  // u16 elements per buffer (A 8192 + B 8192)

__device__ __forceinline__ void stage_tile(const u16* __restrict__ A, const u16* __restrict__ Bt,
                                           u16* lds_buf, int m0, int n0, int K, int k0,
                                           int w, int ln) {
  u16* As = lds_buf;
  u16* Bs = lds_buf + 8192;
#pragma unroll
  for (int i = 0; i < 2; ++i) {
    int idx = i * 512 + w * 64 + ln;
    int rg = idx >> 2;
    int cg = (idx & 3) ^ (rg & 3);
    glds16(A + (size_t)(m0 + rg) * K + k0 + cg * 8, As + ((size_t)(i * 512 + w * 64)) * 8);
  }
#pragma unroll
  for (int i = 0; i < 2; ++i) {
    int idx = i * 512 + w * 64 + ln;
    int rg = idx >> 2;
    int cg = (idx & 3) ^ (rg & 3);
    glds16(Bt + (size_t)(n0 + rg) * K + k0 + cg * 8, Bs + ((size_t)(i * 512 + w * 64)) * 8);
  }
}

__device__ __forceinline__ void compute_tile(const u16* __restrict__ As, const u16* __restrict__ Bs,
                                             int wr, int wc, int lr, int lk, f32x4 acc[8][4]) {
  bf16x8 af[8], bf[4];
#pragma unroll
  for (int mf = 0; mf < 8; ++mf) {
    int row = wr * 128 + mf * 16 + lr;
    af[mf] = *(const bf16x8*)&As[row * 32 + ((lk ^ (row & 3)) * 8)];
  }
#pragma unroll
  for (int nf = 0; nf < 4; ++nf) {
    int row = wc * 64 + nf * 16 + lr;
    bf[nf] = *(const bf16x8*)&Bs[row * 32 + ((lk ^ (row & 3)) * 8)];
  }
#pragma unroll
  for (int mf = 0; mf < 8; ++mf)
#pragma unroll
    for (int nf = 0; nf < 4; ++nf)
      acc[mf][nf] = __builtin_amdgcn_mfma_f32_16x16x32_bf16(af[mf], bf[nf], acc[mf][nf], 0, 0, 0);
}

template <int OUTF32>
__global__ __launch_bounds__(512, 2) void gemm256(const u16* __restrict__ A, const u16* __restrict__ Bt,
                                                  void* __restrict__ C, int M, int N, int K, int NTN) {
  __shared__ __align__(16) u16 lds[4 * GBUF];
  const int tid = threadIdx.x, w = tid >> 6, ln = tid & 63;
  const int lr = ln & 15, lk = ln >> 4;
  const int wr = w >> 2, wc = w & 3;
  // bijective XCD swizzle (grid sizes here are multiples of 8)
  const int nwg = gridDim.x;
  const int cpx = nwg >> 3;
  const int wg = (blockIdx.x & 7) * cpx + (blockIdx.x >> 3);
  const int m0 = (wg / NTN) * 256, n0 = (wg % NTN) * 256;
  f32x4 acc[8][4];
#pragma unroll
  for (int i = 0; i < 8; ++i)
#pragma unroll
    for (int j = 0; j < 4; ++j) acc[i][j] = (f32x4){0.f, 0.f, 0.f, 0.f};
  const int nt = K / 32;
  // prologue: stage tiles 0,1,2 (12 glds16/wave outstanding)
  stage_tile(A, Bt, lds + 0 * GBUF, m0, n0, K, 0, w, ln);
  __builtin_amdgcn_sched_barrier(0);
  stage_tile(A, Bt, lds + 1 * GBUF, m0, n0, K, 32, w, ln);
  __builtin_amdgcn_sched_barrier(0);
  stage_tile(A, Bt, lds + 2 * GBUF, m0, n0, K, 64, w, ln);
  __builtin_amdgcn_sched_barrier(0);
  for (int t = 0; t < nt - 3; ++t) {
    __builtin_amdgcn_sched_barrier(0);
    stage_tile(A, Bt, lds + ((t + 3) & 3) * GBUF, m0, n0, K, (t + 3) * 32, w, ln);
    asm volatile("s_waitcnt vmcnt(12)" ::: "memory");
    __builtin_amdgcn_s_barrier();              // (A) tile t fully resident for all waves
    __builtin_amdgcn_sched_barrier(0);
    const u16* buf = lds + (t & 3) * GBUF;
    compute_tile(buf, buf + 8192, wr, wc, lr, lk, acc);
    __builtin_amdgcn_sched_barrier(0);
    __builtin_amdgcn_s_barrier();              // (B) all reads of tile t done before re-stage
  }
  // tail: tiles nt-3, nt-2, nt-1 (no staging; drain progressively)
  asm volatile("s_waitcnt vmcnt(8)" ::: "memory");
  __builtin_amdgcn_s_barrier();
  __builtin_amdgcn_sched_barrier(0);
  {
    const u16* buf = lds + ((nt - 3) & 3) * GBUF;
    compute_tile(buf, buf + 8192, wr, wc, lr, lk, acc);
  }
  asm volatile("s_waitcnt vmcnt(4)" ::: "memory");
  __builtin_amdgcn_s_barrier();
  __builtin_amdgcn_sched_barrier(0);
  {
    const u16* buf = lds + ((nt - 2) & 3) * GBUF;
    compute_tile(buf, buf + 8192, wr, wc, lr, lk, acc);
  }
  asm volatile("s_waitcnt vmcnt(0)" ::: "memory");
  __builtin_amdgcn_s_barrier();
  __builtin_amdgcn_sched_barrier(0);
  {
    const u16* buf = lds + ((nt - 1) & 3) * GBUF;
    compute_tile(buf, buf + 8192, wr, wc, lr, lk, acc);
  }
  // epilogue
#pragma unroll
  for (int mf = 0; mf < 8; ++mf) {
    int row = m0 + wr * 128 + mf * 16 + lk * 4;
#pragma unroll
    for (int nf = 0; nf < 4; ++nf) {
      int col = n0 + wc * 64 + nf * 16 + lr;
#pragma unroll
      for (int jj = 0; jj < 4; ++jj) {
        float v = acc[mf][nf][jj];
        if (OUTF32) ((float*)C)[(size_t)(row + jj) * N + col] = v;
        else ((u16*)C)[(size_t)(row + jj) * N + col] = f2bf(v);
      }
    }
  }
}

// ---------------- fused attention: 64 q-rows/block, KVB=64, XOR-swizzled LDS ----------------
__global__ __launch_bounds__(256) void k_attn(const u16* __restrict__ q, const u16* __restrict__ kr,
                                              const u16* __restrict__ vt, u16* __restrict__ o,
                                              const float* __restrict__ mixp, int qs) {
  __shared__ __align__(16) u16 Ks[KVB * 128];      // (kpos, d) swizzled
  __shared__ __align__(16) u16 Vs[128 * KVB];      // (d, kpos) swizzled
  __shared__ __align__(16) u16 Ps[4][16 * KVB];    // per-wave (q, kpos) swizzled
  const int tid = threadIdx.x, w = tid >> 6, ln = tid & 63;
  const int lr = ln & 15, lk = ln >> 4;
  const int bid = blockIdx.x;
  const int qblk = (S_ / 64 - 1) - (bid >> 5);     // longest blocks dispatch first
  const int h = bid & 31, kv = h >> 2;
  const bool strm = (*mixp) > 0.5f;
  const int q0 = qblk * 64;
  const int qrow = q0 + w * 16 + lr;
  bf16x8 qf[4];
#pragma unroll
  for (int c = 0; c < 4; ++c)
    qf[c] = *(const bf16x8*)(q + (size_t)qrow * qs + h * D_ + c * 32 + lk * 8);
  f32x4 oacc[8];
#pragma unroll
  for (int c = 0; c < 8; ++c) oacc[c] = (f32x4){0.f, 0.f, 0.f, 0.f};
  float mrun[4], lrun[4];
#pragma unroll
  for (int j = 0; j < 4; ++j) { mrun[j] = -1e30f; lrun[j] = 0.f; }
  const u16* kbase = kr + (size_t)kv * S_ * D_;
  const u16* vbase = vt + (size_t)kv * D_ * S_;
  const int qg0 = q0 + w * 16 + lk * 4;
  const float scale = 0.08838834764831845f;
  const int ntiles = qblk + 1;
  for (int kt = 0; kt < ntiles; ++kt) {
    const int kb0 = kt * KVB;
    if (strm && kb0 >= SINK_ && kb0 + KVB - 1 + WIN_ <= q0) continue;
    __syncthreads();
#pragma unroll
    for (int c = 0; c < 4; ++c) {
      int r0 = c * 16 + w * 4;
      int rg = r0 + (ln >> 4);
      int cg = (ln & 15) ^ (rg & 7);
      glds16(kbase + (size_t)(kb0 + rg) * D_ + cg * 8, &Ks[r0 * 128]);
    }
#pragma unroll
    for (int c = 0; c < 4; ++c) {
      int r0 = c * 32 + w * 8;
      int rg = r0 + (ln >> 3);
      int cg = (ln & 7) ^ (rg & 7);
      glds16(vbase + (size_t)rg * S_ + kb0 + cg * 8, &Vs[r0 * KVB]);
    }
    __syncthreads();
    f32x4 sg[4];
#pragma unroll
    for (int g = 0; g < 4; ++g) sg[g] = (f32x4){0.f, 0.f, 0.f, 0.f};
#pragma unroll
    for (int g = 0; g < 4; ++g) {
      int krow = g * 16 + lr;
      int sw = krow & 7;
#pragma unroll
      for (int c = 0; c < 4; ++c) {
        bf16x8 kf = *(const bf16x8*)&Ks[krow * 128 + (((c * 4 + lk) ^ sw) * 8)];
        sg[g] = __builtin_amdgcn_mfma_f32_16x16x32_bf16(qf[c], kf, sg[g], 0, 0, 0);
      }
    }
    const bool lastt = (kt == qblk);
    const bool needm = lastt ||
        (strm && !(kb0 + KVB <= SINK_ || kb0 >= q0 + 64 - WIN_));
    if (needm) {
#pragma unroll
      for (int g = 0; g < 4; ++g) {
        int kg = kb0 + g * 16 + lr;
#pragma unroll
        for (int j = 0; j < 4; ++j) {
          int qi = qg0 + j;
          float v = sg[g][j] * scale;
          bool ok = (kg <= qi) && (!strm || kg < SINK_ || kg > qi - WIN_);
          sg[g][j] = ok ? v : -1e30f;
        }
      }
    } else {
#pragma unroll
      for (int g = 0; g < 4; ++g)
#pragma unroll
        for (int j = 0; j < 4; ++j) sg[g][j] *= scale;
    }
    float rmax[4];
#pragma unroll
    for (int j = 0; j < 4; ++j)
      rmax[j] = fmaxf(fmaxf(sg[0][j], sg[1][j]), fmaxf(sg[2][j], sg[3][j]));
#pragma unroll
    for (int m2 = 1; m2 < 16; m2 <<= 1)
#pragma unroll
      for (int j = 0; j < 4; ++j) rmax[j] = fmaxf(rmax[j], __shfl_xor(rmax[j], m2));
    float corr[4];
#pragma unroll
    for (int j = 0; j < 4; ++j) {
      float mn = fmaxf(mrun[j], rmax[j]);
      corr[j] = __expf(mrun[j] - mn);
      mrun[j] = mn;
    }
    float rsum[4] = {0.f, 0.f, 0.f, 0.f};
#pragma unroll
    for (int g = 0; g < 4; ++g)
#pragma unroll
      for (int j = 0; j < 4; ++j) {
        float p = __expf(sg[g][j] - mrun[j]);
        sg[g][j] = p;
        rsum[j] += p;
      }
#pragma unroll
    for (int m2 = 1; m2 < 16; m2 <<= 1)
#pragma unroll
      for (int j = 0; j < 4; ++j) rsum[j] += __shfl_xor(rsum[j], m2);
#pragma unroll
    for (int j = 0; j < 4; ++j) lrun[j] = lrun[j] * corr[j] + rsum[j];
#pragma unroll
    for (int c = 0; c < 8; ++c) {
      f32x4 t = oacc[c];
      t[0] *= corr[0]; t[1] *= corr[1]; t[2] *= corr[2]; t[3] *= corr[3];
      oacc[c] = t;
    }
#pragma unroll
    for (int g = 0; g < 4; ++g) {
      int col = g * 16 + lr;
      int c16 = col >> 3;
#pragma unroll
      for (int j = 0; j < 4; ++j) {
        int row = lk * 4 + j;
        Ps[w][row * KVB + ((c16 ^ (row & 7)) * 8) + (col & 7)] = f2bf(sg[g][j]);
      }
    }
#pragma unroll
    for (int half = 0; half < 2; ++half) {
      bf16x8 pf = *(const bf16x8*)&Ps[w][lr * KVB + (((half * 4 + lk) ^ (lr & 7)) * 8)];
#pragma unroll
      for (int cc = 0; cc < 8; ++cc) {
        int vrow = cc * 16 + lr;
        bf16x8 vf = *(const bf16x8*)&Vs[vrow * KVB + (((half * 4 + lk) ^ (vrow & 7)) * 8)];
        oacc[cc] = __builtin_amdgcn_mfma_f32_16x16x32_bf16(pf, vf, oacc[cc], 0, 0, 0);
      }
    }
  }
#pragma unroll
  for (int cc = 0; cc < 8; ++cc)
#pragma unroll
    for (int j = 0; j < 4; ++j) {
      float ov = oacc[cc][j] / lrun[j];
      o[(size_t)(qg0 + j) * HID_ + h * D_ + cc * 16 + lr] = f2bf(ov);
    }
}

extern "C" void kernel_launch(void* const* d_in, const int* in_sizes, int n_in,
                              void* d_out, int out_size, void* d_ws, size_t ws_size,
                              hipStream_t stream) {
  const float* hs = (const float*)d_in[0];
  const float* Wq = (const float*)d_in[1];
  const float* Wk = (const float*)d_in[2];
  const float* Wv = (const float*)d_in[3];
  const float* Wo = (const float*)d_in[4];
  const float* fe1_w = (const float*)d_in[5];
  const float* fe1_b = (const float*)d_in[6];
  const float* fe2_w = (const float*)d_in[7];
  const float* fe2_b = (const float*)d_in[8];
  const float* r1_w = (const float*)d_in[9];
  const float* r1_b = (const float*)d_in[10];
  const float* r2_w = (const float*)d_in[11];
  const float* r2_b = (const float*)d_in[12];
  const float* r3_w = (const float*)d_in[13];
  const float* r3_b = (const float*)d_in[14];
  const float* noise = (const float*)d_in[15];

  char* ws = (char*)d_ws;
  size_t off = 0;
  auto alloc = [&](size_t b) { char* p = ws + off; off += (b + 255) & ~(size_t)255; return p; };
  u16* hsb = (u16*)alloc((size_t)S_ * HID_ * 2);
  u16* wqkv = (u16*)alloc((size_t)QKVN * HID_ * 2);  // [Wq^T; Wk^T; Wv^T]; later reused for Wo^T
  u16* qkvbuf = (u16*)alloc((size_t)S_ * QKVN * 2);  // cols: 0..4095 q | 4096..5119 k | 5120..6143 v
  u16* krbuf = (u16*)alloc((size_t)S_ * KVD_ * 2);
  u16* vtbuf = (u16*)alloc((size_t)S_ * KVD_ * 2);
  u16* obuf = (u16*)alloc((size_t)S_ * HID_ * 2);
  float* cosT = (float*)alloc((size_t)S_ * 64 * 4);
  float* sinT = (float*)alloc((size_t)S_ * 64 * 4);
  float* feat = (float*)alloc(512);
  float* mix = (float*)alloc(256);

  k_f32_to_bf16<<<dim3(S_ * HID_ / 4 / 256), dim3(256), 0, stream>>>(hs, hsb, S_ * HID_ / 4);
  k_transpose_w<<<dim3(HID_ / 32, HID_ / 32), dim3(256), 0, stream>>>(Wq, wqkv, HID_, HID_);
  k_transpose_w<<<dim3(KVD_ / 32, HID_ / 32), dim3(256), 0, stream>>>(Wk, wqkv + (size_t)4096 * HID_, HID_, KVD_);
  k_transpose_w<<<dim3(KVD_ / 32, HID_ / 32), dim3(256), 0, stream>>>(Wv, wqkv + (size_t)5120 * HID_, HID_, KVD_);
  k_rope_table<<<dim3(S_ * 64 / 256), dim3(256), 0, stream>>>(cosT, sinT);

  // fused QKV GEMM: M=2048, N=6144, K=4096 -> 8x24 = 192 blocks
  gemm256<0><<<dim3((S_ / 256) * (QKVN / 256)), dim3(512), 0, stream>>>(hsb, wqkv, (void*)qkvbuf,
                                                                        S_, QKVN, HID_, QKVN / 256);

  k_rope_q<<<dim3(S_ * H_ * 64 / 256), dim3(256), 0, stream>>>(qkvbuf, cosT, sinT);
  k_rope_k<<<dim3(S_ * KV_ * 64 / 256), dim3(256), 0, stream>>>(qkvbuf, krbuf, cosT, sinT);
  k_transpose_v<<<dim3(S_ / 32, D_ / 32, KV_), dim3(256), 0, stream>>>(qkvbuf, vtbuf);

  k_feat<<<dim3(D_), dim3(256), 0, stream>>>(qkvbuf, feat);
  k_router<<<dim3(1), dim3(256), 0, stream>>>(feat, fe1_w, fe1_b, fe2_w, fe2_b,
                                              r1_w, r1_b, r2_w, r2_b, r3_w, r3_b, noise, mix);

  k_attn<<<dim3((S_ / 64) * H_), dim3(256), 0, stream>>>(qkvbuf, krbuf, vtbuf, obuf, mix, QKVN);

  // Wo^T reuses the wqkv slot (QKV GEMM is complete by stream order)
  k_transpose_w<<<dim3(HID_ / 32, HID_ / 32), dim3(256), 0, stream>>>(Wo, wqkv, HID_, HID_);
  gemm256<1><<<dim3((S_ / 256) * (HID_ / 256)), dim3(512), 0, stream>>>(obuf, wqkv, d_out,
                                                                        S_, HID_, HID_, HID_ / 256);
}

// Round 4
// 490.234 us; speedup vs baseline: 1.7674x; 1.0660x over previous
//
#include <hip/hip_runtime.h>
#include <hip/hip_bf16.h>

typedef unsigned short u16;
typedef unsigned int u32;
typedef __bf16 bf16x8 __attribute__((ext_vector_type(8)));
typedef float f32x4 __attribute__((ext_vector_type(4)));

#define S_ 2048
#define H_ 32
#define KV_ 8
#define D_ 128
#define HID_ 4096
#define KVD_ 1024
#define QKVN 6144
#define SINK_ 128
#define WIN_ 1024
#define POOL_ 100
#define KVB 64

__device__ __forceinline__ u16 f2bf(float f) {
  union { float f; u32 u; } v; v.f = f;
  u32 r = v.u + 0x7FFFu + ((v.u >> 16) & 1u);
  return (u16)(r >> 16);
}
__device__ __forceinline__ float bf2f(u16 h) {
  union { u32 u; float f; } v; v.u = ((u32)h) << 16;
  return v.f;
}
// async global->LDS, 16B per lane. LDS dest is wave-uniform base; HW writes base + lane*16.
__device__ __forceinline__ void glds16(const void* g, void* l) {
  __builtin_amdgcn_global_load_lds((__attribute__((address_space(1))) void*)g,
                                   (__attribute__((address_space(3))) void*)l, 16, 0, 0);
}

// ---------------- elementwise fp32 -> bf16 (4/thread) ----------------
__global__ void k_f32_to_bf16(const float* __restrict__ x, u16* __restrict__ y, int n4) {
  int i = blockIdx.x * 256 + threadIdx.x;
  if (i >= n4) return;
  float4 v = ((const float4*)x)[i];
  union { u16 s[4]; unsigned long long ll; } o;
  o.s[0] = f2bf(v.x); o.s[1] = f2bf(v.y); o.s[2] = f2bf(v.z); o.s[3] = f2bf(v.w);
  ((unsigned long long*)y)[i] = o.ll;
}

// ---------------- W (K,N) fp32 -> Wt (N,K) bf16, 32x32 LDS tile ----------------
__global__ void k_transpose_w(const float* __restrict__ W, u16* __restrict__ Wt, int K, int N) {
  __shared__ u16 T[32][33];
  int nt = blockIdx.x, kt = blockIdx.y;
  int c = threadIdx.x & 31, r0 = threadIdx.x >> 5;
#pragma unroll
  for (int p = 0; p < 4; ++p) {
    int r = r0 + p * 8;
    T[r][c] = f2bf(W[(size_t)(kt * 32 + r) * N + nt * 32 + c]);
  }
  __syncthreads();
#pragma unroll
  for (int p = 0; p < 4; ++p) {
    int r = r0 + p * 8;
    Wt[(size_t)(nt * 32 + r) * K + kt * 32 + c] = T[c][r];
  }
}

// ---------------- v (cols 5120.. of qkv buf) bf16 -> vt (kv, d, s) bf16 ----------------
__global__ void k_transpose_v(const u16* __restrict__ v, u16* __restrict__ vt) {
  __shared__ u16 T[32][33];
  int st = blockIdx.x, dt = blockIdx.y, kv = blockIdx.z;
  int c = threadIdx.x & 31, r0 = threadIdx.x >> 5;
#pragma unroll
  for (int p = 0; p < 4; ++p) {
    int r = r0 + p * 8;
    T[r][c] = v[(size_t)(st * 32 + r) * QKVN + 5120 + kv * D_ + dt * 32 + c];
  }
  __syncthreads();
#pragma unroll
  for (int p = 0; p < 4; ++p) {
    int r = r0 + p * 8;
    vt[(size_t)kv * D_ * S_ + (size_t)(dt * 32 + r) * S_ + st * 32 + c] = T[c][r];
  }
}

// ---------------- RoPE tables ----------------
__global__ void k_rope_table(float* __restrict__ cosT, float* __restrict__ sinT) {
  int idx = blockIdx.x * 256 + threadIdx.x;
  if (idx >= S_ * 64) return;
  int s = idx >> 6, i = idx & 63;
  float inv = powf(10000.f, -(float)i * (1.f / 64.f));
  float ang = (float)s * inv;
  cosT[idx] = cosf(ang);
  sinT[idx] = sinf(ang);
}

// ---------------- RoPE on q in-place (qkv buf, row stride QKVN) ----------------
__global__ void k_rope_q(u16* __restrict__ q, const float* __restrict__ cosT, const float* __restrict__ sinT) {
  int idx = blockIdx.x * 256 + threadIdx.x;
  if (idx >= S_ * H_ * 64) return;
  int i = idx & 63, h = (idx >> 6) & 31, s = idx >> 11;
  size_t base = (size_t)s * QKVN + h * D_ + i;
  float x1 = bf2f(q[base]), x2 = bf2f(q[base + 64]);
  float cs = cosT[(s << 6) + i], sn = sinT[(s << 6) + i];
  q[base] = f2bf(x1 * cs - x2 * sn);
  q[base + 64] = f2bf(x2 * cs + x1 * sn);
}

// ---------------- RoPE on k (qkv buf cols 4096..), relayout -> (kv, s, 128) ----------------
__global__ void k_rope_k(const u16* __restrict__ k, u16* __restrict__ kro,
                         const float* __restrict__ cosT, const float* __restrict__ sinT) {
  int idx = blockIdx.x * 256 + threadIdx.x;
  if (idx >= S_ * KV_ * 64) return;
  int i = idx & 63, kv = (idx >> 6) & 7, s = idx >> 9;
  float x1 = bf2f(k[(size_t)s * QKVN + 4096 + kv * D_ + i]);
  float x2 = bf2f(k[(size_t)s * QKVN + 4096 + kv * D_ + i + 64]);
  float cs = cosT[(s << 6) + i], sn = sinT[(s << 6) + i];
  size_t ob = (size_t)kv * S_ * D_ + (size_t)s * D_ + i;
  kro[ob] = f2bf(x1 * cs - x2 * sn);
  kro[ob + 64] = f2bf(x2 * cs + x1 * sn);
}

// ---------------- pooled feature ----------------
__global__ void k_feat(const u16* __restrict__ q, float* __restrict__ feat) {
  int d = blockIdx.x, tid = threadIdx.x;
  float p = 0.f;
  for (int idx = tid; idx < 2 * POOL_ * H_; idx += 256) {
    int pos = idx >> 5, hh = idx & 31;
    int s = pos < POOL_ ? pos : (S_ - 2 * POOL_) + pos;
    p += bf2f(q[(size_t)s * QKVN + hh * D_ + d]);
  }
#pragma unroll
  for (int m = 1; m < 64; m <<= 1) p += __shfl_xor(p, m);
  __shared__ float red[4];
  if ((tid & 63) == 0) red[tid >> 6] = p;
  __syncthreads();
  if (tid == 0) feat[d] = (red[0] + red[1] + red[2] + red[3]) * (1.f / (2 * POOL_ * H_));
}

// ---------------- router MLP (fp32, single block) ----------------
__global__ void k_router(const float* __restrict__ feat,
                         const float* __restrict__ fe1_w, const float* __restrict__ fe1_b,
                         const float* __restrict__ fe2_w, const float* __restrict__ fe2_b,
                         const float* __restrict__ r1_w, const float* __restrict__ r1_b,
                         const float* __restrict__ r2_w, const float* __restrict__ r2_b,
                         const float* __restrict__ r3_w, const float* __restrict__ r3_b,
                         const float* __restrict__ noise, float* __restrict__ mix) {
  __shared__ float fs[128], h1[1024], h2[256], h3[512], h4[128];
  int tid = threadIdx.x;
  if (tid < 128) fs[tid] = feat[tid];
  __syncthreads();
  for (int o = tid; o < 1024; o += 256) {
    float a = fe1_b[o];
    for (int kk = 0; kk < 128; ++kk) a += fs[kk] * fe1_w[kk * 1024 + o];
    h1[o] = a / (1.f + expf(-a));
  }
  __syncthreads();
  {
    float a = fe2_b[tid];
    for (int kk = 0; kk < 1024; ++kk) a += h1[kk] * fe2_w[kk * 256 + tid];
    h2[tid] = a;
  }
  __syncthreads();
  for (int o = tid; o < 512; o += 256) {
    float a = r1_b[o];
    for (int kk = 0; kk < 256; ++kk) a += h2[kk] * r1_w[kk * 512 + o];
    h3[o] = a / (1.f + expf(-a));
  }
  __syncthreads();
  if (tid < 128) {
    float a = r2_b[tid];
    for (int kk = 0; kk < 512; ++kk) a += h3[kk] * r2_w[kk * 128 + tid];
    h4[tid] = a / (1.f + expf(-a));
  }
  __syncthreads();
  if (tid == 0) {
    float a = r3_b[0];
    for (int kk = 0; kk < 128; ++kk) a += h4[kk] * r3_w[kk];
    float u = noise[0];
    float g = -logf(-logf(u + 1e-8f) + 1e-8f);
    float zs = 1.f / (1.f + expf(-(a + g)));
    mix[0] = zs > 0.5f ? 1.f : 0.f;
  }
}

// ============ 128x256 GEMM, BK=32, 3-buf counted-vmcnt pipeline ============
// C(M,N) = A(M,K) @ Bt(N,K)^T. 4 waves (1M x 4N), per-wave 128x64 out
// (32 MFMA : 12 ds_read_b128). LDS 3 bufs x 24 KiB = 72 KiB -> 2 blocks/CU.
// Swizzle: 16B cell (row, c) holds global chunk c ^ ((row>>1)&3): fragment
// reads (16 rows, stride 64 B) land 2-way max per bank (free, m136).
#define GBUF 12288  // u16 per buffer: A 128x32 (4096) + B 256x32 (8192)

__device__ __forceinline__ void stage_tile(const u16* __restrict__ A, const u16* __restrict__ Bt,
                                           u16* lds_buf, int m0, int n0, int K, int k0,
                                           int w, int ln) {
  u16* As = lds_buf;
  u16* Bs = lds_buf + 4096;
#pragma unroll
  for (int j = 0; j < 2; ++j) {
    int base = j * 256 + w * 64;
    int idx = base + ln;
    int r = idx >> 2;
    int cg = (idx & 3) ^ ((r >> 1) & 3);
    glds16(A + (size_t)(m0 + r) * K + k0 + cg * 8, As + (size_t)base * 8);
  }
#pragma unroll
  for (int j = 0; j < 4; ++j) {
    int base = j * 256 + w * 64;
    int idx = base + ln;
    int r = idx >> 2;
    int cg = (idx & 3) ^ ((r >> 1) & 3);
    glds16(Bt + (size_t)(n0 + r) * K + k0 + cg * 8, Bs + (size_t)base * 8);
  }
}

__device__ __forceinline__ void compute_tile(const u16* __restrict__ As, const u16* __restrict__ Bs,
                                             int wc, int lr, int lk, f32x4 acc[8][4]) {
  bf16x8 af[8], bf[4];
#pragma unroll
  for (int mf = 0; mf < 8; ++mf) {
    int row = mf * 16 + lr;
    af[mf] = *(const bf16x8*)&As[row * 32 + ((lk ^ ((row >> 1) & 3)) * 8)];
  }
#pragma unroll
  for (int nf = 0; nf < 4; ++nf) {
    int row = wc * 64 + nf * 16 + lr;
    bf[nf] = *(const bf16x8*)&Bs[row * 32 + ((lk ^ ((row >> 1) & 3)) * 8)];
  }
#pragma unroll
  for (int mf = 0; mf < 8; ++mf)
#pragma unroll
    for (int nf = 0; nf < 4; ++nf)
      acc[mf][nf] = __builtin_amdgcn_mfma_f32_16x16x32_bf16(af[mf], bf[nf], acc[mf][nf], 0, 0, 0);
}

template <int OUTF32>
__global__ __launch_bounds__(256, 2) void gemm128(const u16* __restrict__ A, const u16* __restrict__ Bt,
                                                  void* __restrict__ C, int M, int N, int K, int NTN) {
  __shared__ __align__(16) u16 lds[3 * GBUF];
  const int tid = threadIdx.x, w = tid >> 6, ln = tid & 63;
  const int lr = ln & 15, lk = ln >> 4;
  const int wc = w;
  // bijective XCD swizzle (grid sizes here are multiples of 8)
  const int nwg = gridDim.x;
  const int cpx = nwg >> 3;
  const int wg = (blockIdx.x & 7) * cpx + (blockIdx.x >> 3);
  const int m0 = (wg / NTN) * 128, n0 = (wg % NTN) * 256;
  f32x4 acc[8][4];
#pragma unroll
  for (int i = 0; i < 8; ++i)
#pragma unroll
    for (int j = 0; j < 4; ++j) acc[i][j] = (f32x4){0.f, 0.f, 0.f, 0.f};
  const int nt = K / 32;
  // prologue: stage tiles 0,1 (12 glds16/wave outstanding)
  stage_tile(A, Bt, lds + 0 * GBUF, m0, n0, K, 0, w, ln);
  __builtin_amdgcn_sched_barrier(0);
  stage_tile(A, Bt, lds + 1 * GBUF, m0, n0, K, 32, w, ln);
  __builtin_amdgcn_sched_barrier(0);
  int b0 = 0, b1 = 1, b2 = 2;  // rotating buffer indices (avoid % in loop)
  for (int t = 0; t < nt - 2; ++t) {
    __builtin_amdgcn_sched_barrier(0);
    stage_tile(A, Bt, lds + b2 * GBUF, m0, n0, K, (t + 2) * 32, w, ln);
    asm volatile("s_waitcnt vmcnt(12)" ::: "memory");
    __builtin_amdgcn_s_barrier();              // tile t resident for all waves
    __builtin_amdgcn_sched_barrier(0);
    const u16* buf = lds + b0 * GBUF;
    compute_tile(buf, buf + 4096, wc, lr, lk, acc);
    __builtin_amdgcn_sched_barrier(0);
    __builtin_amdgcn_s_barrier();              // reads of tile t done before its buffer re-stage
    int bt = b0; b0 = b1; b1 = b2; b2 = bt;
  }
  // tail: tiles nt-2, nt-1
  asm volatile("s_waitcnt vmcnt(6)" ::: "memory");
  __builtin_amdgcn_s_barrier();
  __builtin_amdgcn_sched_barrier(0);
  {
    const u16* buf = lds + b0 * GBUF;
    compute_tile(buf, buf + 4096, wc, lr, lk, acc);
  }
  asm volatile("s_waitcnt vmcnt(0)" ::: "memory");
  __builtin_amdgcn_s_barrier();
  __builtin_amdgcn_sched_barrier(0);
  {
    const u16* buf = lds + b1 * GBUF;
    compute_tile(buf, buf + 4096, wc, lr, lk, acc);
  }
  // epilogue
#pragma unroll
  for (int mf = 0; mf < 8; ++mf) {
    int row = m0 + mf * 16 + lk * 4;
#pragma unroll
    for (int nf = 0; nf < 4; ++nf) {
      int col = n0 + wc * 64 + nf * 16 + lr;
#pragma unroll
      for (int jj = 0; jj < 4; ++jj) {
        float v = acc[mf][nf][jj];
        if (OUTF32) ((float*)C)[(size_t)(row + jj) * N + col] = v;
        else ((u16*)C)[(size_t)(row + jj) * N + col] = f2bf(v);
      }
    }
  }
}

// ---------------- fused attention: 64 q-rows/block, KVB=64, XOR-swizzled LDS ----------------
__global__ __launch_bounds__(256) void k_attn(const u16* __restrict__ q, const u16* __restrict__ kr,
                                              const u16* __restrict__ vt, u16* __restrict__ o,
                                              const float* __restrict__ mixp, int qs) {
  __shared__ __align__(16) u16 Ks[KVB * 128];      // (kpos, d) swizzled
  __shared__ __align__(16) u16 Vs[128 * KVB];      // (d, kpos) swizzled
  __shared__ __align__(16) u16 Ps[4][16 * KVB];    // per-wave (q, kpos) swizzled
  const int tid = threadIdx.x, w = tid >> 6, ln = tid & 63;
  const int lr = ln & 15, lk = ln >> 4;
  const int bid = blockIdx.x;
  const int qblk = (S_ / 64 - 1) - (bid >> 5);     // longest blocks dispatch first
  const int h = bid & 31, kv = h >> 2;
  const bool strm = (*mixp) > 0.5f;
  const int q0 = qblk * 64;
  const int qrow = q0 + w * 16 + lr;
  bf16x8 qf[4];
#pragma unroll
  for (int c = 0; c < 4; ++c)
    qf[c] = *(const bf16x8*)(q + (size_t)qrow * qs + h * D_ + c * 32 + lk * 8);
  f32x4 oacc[8];
#pragma unroll
  for (int c = 0; c < 8; ++c) oacc[c] = (f32x4){0.f, 0.f, 0.f, 0.f};
  float mrun[4], lrun[4];
#pragma unroll
  for (int j = 0; j < 4; ++j) { mrun[j] = -1e30f; lrun[j] = 0.f; }
  const u16* kbase = kr + (size_t)kv * S_ * D_;
  const u16* vbase = vt + (size_t)kv * D_ * S_;
  const int qg0 = q0 + w * 16 + lk * 4;
  const float scale = 0.08838834764831845f;
  const int ntiles = qblk + 1;
  for (int kt = 0; kt < ntiles; ++kt) {
    const int kb0 = kt * KVB;
    if (strm && kb0 >= SINK_ && kb0 + KVB - 1 + WIN_ <= q0) continue;
    __syncthreads();
#pragma unroll
    for (int c = 0; c < 4; ++c) {
      int r0 = c * 16 + w * 4;
      int rg = r0 + (ln >> 4);
      int cg = (ln & 15) ^ (rg & 7);
      glds16(kbase + (size_t)(kb0 + rg) * D_ + cg * 8, &Ks[r0 * 128]);
    }
#pragma unroll
    for (int c = 0; c < 4; ++c) {
      int r0 = c * 32 + w * 8;
      int rg = r0 + (ln >> 3);
      int cg = (ln & 7) ^ (rg & 7);
      glds16(vbase + (size_t)rg * S_ + kb0 + cg * 8, &Vs[r0 * KVB]);
    }
    __syncthreads();
    f32x4 sg[4];
#pragma unroll
    for (int g = 0; g < 4; ++g) sg[g] = (f32x4){0.f, 0.f, 0.f, 0.f};
#pragma unroll
    for (int g = 0; g < 4; ++g) {
      int krow = g * 16 + lr;
      int sw = krow & 7;
#pragma unroll
      for (int c = 0; c < 4; ++c) {
        bf16x8 kf = *(const bf16x8*)&Ks[krow * 128 + (((c * 4 + lk) ^ sw) * 8)];
        sg[g] = __builtin_amdgcn_mfma_f32_16x16x32_bf16(qf[c], kf, sg[g], 0, 0, 0);
      }
    }
    const bool lastt = (kt == qblk);
    const bool needm = lastt ||
        (strm && !(kb0 + KVB <= SINK_ || kb0 >= q0 + 64 - WIN_));
    if (needm) {
#pragma unroll
      for (int g = 0; g < 4; ++g) {
        int kg = kb0 + g * 16 + lr;
#pragma unroll
        for (int j = 0; j < 4; ++j) {
          int qi = qg0 + j;
          float v = sg[g][j] * scale;
          bool ok = (kg <= qi) && (!strm || kg < SINK_ || kg > qi - WIN_);
          sg[g][j] = ok ? v : -1e30f;
        }
      }
    } else {
#pragma unroll
      for (int g = 0; g < 4; ++g)
#pragma unroll
        for (int j = 0; j < 4; ++j) sg[g][j] *= scale;
    }
    float rmax[4];
#pragma unroll
    for (int j = 0; j < 4; ++j)
      rmax[j] = fmaxf(fmaxf(sg[0][j], sg[1][j]), fmaxf(sg[2][j], sg[3][j]));
#pragma unroll
    for (int m2 = 1; m2 < 16; m2 <<= 1)
#pragma unroll
      for (int j = 0; j < 4; ++j) rmax[j] = fmaxf(rmax[j], __shfl_xor(rmax[j], m2));
    // T13 defer-max: skip rescale when per-tile max growth <= 8 (P bounded by e^8)
    float dmax = rmax[0] - mrun[0];
#pragma unroll
    for (int j = 1; j < 4; ++j) dmax = fmaxf(dmax, rmax[j] - mrun[j]);
    if (!__all(dmax <= 8.f)) {
      float corr[4];
#pragma unroll
      for (int j = 0; j < 4; ++j) {
        float mn = fmaxf(mrun[j], rmax[j]);
        corr[j] = __expf(mrun[j] - mn);
        mrun[j] = mn;
        lrun[j] *= corr[j];
      }
#pragma unroll
      for (int c = 0; c < 8; ++c) {
        f32x4 t = oacc[c];
        t[0] *= corr[0]; t[1] *= corr[1]; t[2] *= corr[2]; t[3] *= corr[3];
        oacc[c] = t;
      }
    }
    float rsum[4] = {0.f, 0.f, 0.f, 0.f};
#pragma unroll
    for (int g = 0; g < 4; ++g)
#pragma unroll
      for (int j = 0; j < 4; ++j) {
        float p = __expf(sg[g][j] - mrun[j]);
        sg[g][j] = p;
        rsum[j] += p;
      }
#pragma unroll
    for (int m2 = 1; m2 < 16; m2 <<= 1)
#pragma unroll
      for (int j = 0; j < 4; ++j) rsum[j] += __shfl_xor(rsum[j], m2);
#pragma unroll
    for (int j = 0; j < 4; ++j) lrun[j] += rsum[j];
#pragma unroll
    for (int g = 0; g < 4; ++g) {
      int col = g * 16 + lr;
      int c16 = col >> 3;
#pragma unroll
      for (int j = 0; j < 4; ++j) {
        int row = lk * 4 + j;
        Ps[w][row * KVB + ((c16 ^ (row & 7)) * 8) + (col & 7)] = f2bf(sg[g][j]);
      }
    }
#pragma unroll
    for (int half = 0; half < 2; ++half) {
      bf16x8 pf = *(const bf16x8*)&Ps[w][lr * KVB + (((half * 4 + lk) ^ (lr & 7)) * 8)];
#pragma unroll
      for (int cc = 0; cc < 8; ++cc) {
        int vrow = cc * 16 + lr;
        bf16x8 vf = *(const bf16x8*)&Vs[vrow * KVB + (((half * 4 + lk) ^ (vrow & 7)) * 8)];
        oacc[cc] = __builtin_amdgcn_mfma_f32_16x16x32_bf16(pf, vf, oacc[cc], 0, 0, 0);
      }
    }
  }
#pragma unroll
  for (int cc = 0; cc < 8; ++cc)
#pragma unroll
    for (int j = 0; j < 4; ++j) {
      float ov = oacc[cc][j] / lrun[j];
      o[(size_t)(qg0 + j) * HID_ + h * D_ + cc * 16 + lr] = f2bf(ov);
    }
}

extern "C" void kernel_launch(void* const* d_in, const int* in_sizes, int n_in,
                              void* d_out, int out_size, void* d_ws, size_t ws_size,
                              hipStream_t stream) {
  const float* hs = (const float*)d_in[0];
  const float* Wq = (const float*)d_in[1];
  const float* Wk = (const float*)d_in[2];
  const float* Wv = (const float*)d_in[3];
  const float* Wo = (const float*)d_in[4];
  const float* fe1_w = (const float*)d_in[5];
  const float* fe1_b = (const float*)d_in[6];
  const float* fe2_w = (const float*)d_in[7];
  const float* fe2_b = (const float*)d_in[8];
  const float* r1_w = (const float*)d_in[9];
  const float* r1_b = (const float*)d_in[10];
  const float* r2_w = (const float*)d_in[11];
  const float* r2_b = (const float*)d_in[12];
  const float* r3_w = (const float*)d_in[13];
  const float* r3_b = (const float*)d_in[14];
  const float* noise = (const float*)d_in[15];

  char* ws = (char*)d_ws;
  size_t off = 0;
  auto alloc = [&](size_t b) { char* p = ws + off; off += (b + 255) & ~(size_t)255; return p; };
  u16* hsb = (u16*)alloc((size_t)S_ * HID_ * 2);
  u16* wqkv = (u16*)alloc((size_t)QKVN * HID_ * 2);  // [Wq^T; Wk^T; Wv^T]; later reused for Wo^T
  u16* qkvbuf = (u16*)alloc((size_t)S_ * QKVN * 2);  // cols: 0..4095 q | 4096..5119 k | 5120..6143 v
  u16* krbuf = (u16*)alloc((size_t)S_ * KVD_ * 2);
  u16* vtbuf = (u16*)alloc((size_t)S_ * KVD_ * 2);
  u16* obuf = (u16*)alloc((size_t)S_ * HID_ * 2);
  float* cosT = (float*)alloc((size_t)S_ * 64 * 4);
  float* sinT = (float*)alloc((size_t)S_ * 64 * 4);
  float* feat = (float*)alloc(512);
  float* mix = (float*)alloc(256);

  k_f32_to_bf16<<<dim3(S_ * HID_ / 4 / 256), dim3(256), 0, stream>>>(hs, hsb, S_ * HID_ / 4);
  k_transpose_w<<<dim3(HID_ / 32, HID_ / 32), dim3(256), 0, stream>>>(Wq, wqkv, HID_, HID_);
  k_transpose_w<<<dim3(KVD_ / 32, HID_ / 32), dim3(256), 0, stream>>>(Wk, wqkv + (size_t)4096 * HID_, HID_, KVD_);
  k_transpose_w<<<dim3(KVD_ / 32, HID_ / 32), dim3(256), 0, stream>>>(Wv, wqkv + (size_t)5120 * HID_, HID_, KVD_);
  k_rope_table<<<dim3(S_ * 64 / 256), dim3(256), 0, stream>>>(cosT, sinT);

  // fused QKV GEMM: M=2048, N=6144, K=4096 -> 16x24 = 384 blocks
  gemm128<0><<<dim3((S_ / 128) * (QKVN / 256)), dim3(256), 0, stream>>>(hsb, wqkv, (void*)qkvbuf,
                                                                        S_, QKVN, HID_, QKVN / 256);

  k_rope_q<<<dim3(S_ * H_ * 64 / 256), dim3(256), 0, stream>>>(qkvbuf, cosT, sinT);
  k_rope_k<<<dim3(S_ * KV_ * 64 / 256), dim3(256), 0, stream>>>(qkvbuf, krbuf, cosT, sinT);
  k_transpose_v<<<dim3(S_ / 32, D_ / 32, KV_), dim3(256), 0, stream>>>(qkvbuf, vtbuf);

  k_feat<<<dim3(D_), dim3(256), 0, stream>>>(qkvbuf, feat);
  k_router<<<dim3(1), dim3(256), 0, stream>>>(feat, fe1_w, fe1_b, fe2_w, fe2_b,
                                              r1_w, r1_b, r2_w, r2_b, r3_w, r3_b, noise, mix);

  k_attn<<<dim3((S_ / 64) * H_), dim3(256), 0, stream>>>(qkvbuf, krbuf, vtbuf, obuf, mix, QKVN);

  // Wo^T reuses the wqkv slot (QKV GEMM is complete by stream order)
  k_transpose_w<<<dim3(HID_ / 32, HID_ / 32), dim3(256), 0, stream>>>(Wo, wqkv, HID_, HID_);
  // Wo GEMM: M=2048, N=4096 -> 16x16 = 256 blocks (full CU coverage)
  gemm128<1><<<dim3((S_ / 128) * (HID_ / 256)), dim3(256), 0, stream>>>(obuf, wqkv, d_out,
                                                                        S_, HID_, HID_, HID_ / 256);
}

// Round 5
// 460.415 us; speedup vs baseline: 1.8819x; 1.0648x over previous
//
#include <hip/hip_runtime.h>
#include <hip/hip_bf16.h>

typedef unsigned short u16;
typedef unsigned int u32;
typedef __bf16 bf16x8 __attribute__((ext_vector_type(8)));
typedef float f32x4 __attribute__((ext_vector_type(4)));

#define S_ 2048
#define H_ 32
#define KV_ 8
#define D_ 128
#define HID_ 4096
#define KVD_ 1024
#define QKVN 6144
#define SINK_ 128
#define WIN_ 1024
#define POOL_ 100
#define KVB 64

__device__ __forceinline__ u16 f2bf(float f) {
  union { float f; u32 u; } v; v.f = f;
  u32 r = v.u + 0x7FFFu + ((v.u >> 16) & 1u);
  return (u16)(r >> 16);
}
__device__ __forceinline__ float bf2f(u16 h) {
  union { u32 u; float f; } v; v.u = ((u32)h) << 16;
  return v.f;
}
// async global->LDS, 16B per lane. LDS dest is wave-uniform base; HW writes base + lane*16.
__device__ __forceinline__ void glds16(const void* g, void* l) {
  __builtin_amdgcn_global_load_lds((__attribute__((address_space(1))) void*)g,
                                   (__attribute__((address_space(3))) void*)l, 16, 0, 0);
}

// ---------------- elementwise fp32 -> bf16 (4/thread) ----------------
__global__ void k_f32_to_bf16(const float* __restrict__ x, u16* __restrict__ y, int n4) {
  int i = blockIdx.x * 256 + threadIdx.x;
  if (i >= n4) return;
  float4 v = ((const float4*)x)[i];
  union { u16 s[4]; unsigned long long ll; } o;
  o.s[0] = f2bf(v.x); o.s[1] = f2bf(v.y); o.s[2] = f2bf(v.z); o.s[3] = f2bf(v.w);
  ((unsigned long long*)y)[i] = o.ll;
}

// ---------------- W (K,N) fp32 -> Wt (N,K) bf16, 32x32 LDS tile ----------------
__global__ void k_transpose_w(const float* __restrict__ W, u16* __restrict__ Wt, int K, int N) {
  __shared__ u16 T[32][33];
  int nt = blockIdx.x, kt = blockIdx.y;
  int c = threadIdx.x & 31, r0 = threadIdx.x >> 5;
#pragma unroll
  for (int p = 0; p < 4; ++p) {
    int r = r0 + p * 8;
    T[r][c] = f2bf(W[(size_t)(kt * 32 + r) * N + nt * 32 + c]);
  }
  __syncthreads();
#pragma unroll
  for (int p = 0; p < 4; ++p) {
    int r = r0 + p * 8;
    Wt[(size_t)(nt * 32 + r) * K + kt * 32 + c] = T[c][r];
  }
}

// ---------------- v (cols 5120.. of qkv buf) bf16 -> vt (kv, d, s) bf16 ----------------
__global__ void k_transpose_v(const u16* __restrict__ v, u16* __restrict__ vt) {
  __shared__ u16 T[32][33];
  int st = blockIdx.x, dt = blockIdx.y, kv = blockIdx.z;
  int c = threadIdx.x & 31, r0 = threadIdx.x >> 5;
#pragma unroll
  for (int p = 0; p < 4; ++p) {
    int r = r0 + p * 8;
    T[r][c] = v[(size_t)(st * 32 + r) * QKVN + 5120 + kv * D_ + dt * 32 + c];
  }
  __syncthreads();
#pragma unroll
  for (int p = 0; p < 4; ++p) {
    int r = r0 + p * 8;
    vt[(size_t)kv * D_ * S_ + (size_t)(dt * 32 + r) * S_ + st * 32 + c] = T[c][r];
  }
}

// ---------------- RoPE tables ----------------
__global__ void k_rope_table(float* __restrict__ cosT, float* __restrict__ sinT) {
  int idx = blockIdx.x * 256 + threadIdx.x;
  if (idx >= S_ * 64) return;
  int s = idx >> 6, i = idx & 63;
  float inv = powf(10000.f, -(float)i * (1.f / 64.f));
  float ang = (float)s * inv;
  cosT[idx] = cosf(ang);
  sinT[idx] = sinf(ang);
}

// ---------------- RoPE on q in-place (qkv buf, row stride QKVN) ----------------
__global__ void k_rope_q(u16* __restrict__ q, const float* __restrict__ cosT, const float* __restrict__ sinT) {
  int idx = blockIdx.x * 256 + threadIdx.x;
  if (idx >= S_ * H_ * 64) return;
  int i = idx & 63, h = (idx >> 6) & 31, s = idx >> 11;
  size_t base = (size_t)s * QKVN + h * D_ + i;
  float x1 = bf2f(q[base]), x2 = bf2f(q[base + 64]);
  float cs = cosT[(s << 6) + i], sn = sinT[(s << 6) + i];
  q[base] = f2bf(x1 * cs - x2 * sn);
  q[base + 64] = f2bf(x2 * cs + x1 * sn);
}

// ---------------- RoPE on k (qkv buf cols 4096..), relayout -> (kv, s, 128) ----------------
__global__ void k_rope_k(const u16* __restrict__ k, u16* __restrict__ kro,
                         const float* __restrict__ cosT, const float* __restrict__ sinT) {
  int idx = blockIdx.x * 256 + threadIdx.x;
  if (idx >= S_ * KV_ * 64) return;
  int i = idx & 63, kv = (idx >> 6) & 7, s = idx >> 9;
  float x1 = bf2f(k[(size_t)s * QKVN + 4096 + kv * D_ + i]);
  float x2 = bf2f(k[(size_t)s * QKVN + 4096 + kv * D_ + i + 64]);
  float cs = cosT[(s << 6) + i], sn = sinT[(s << 6) + i];
  size_t ob = (size_t)kv * S_ * D_ + (size_t)s * D_ + i;
  kro[ob] = f2bf(x1 * cs - x2 * sn);
  kro[ob + 64] = f2bf(x2 * cs + x1 * sn);
}

// ---------------- pooled feature ----------------
__global__ void k_feat(const u16* __restrict__ q, float* __restrict__ feat) {
  int d = blockIdx.x, tid = threadIdx.x;
  float p = 0.f;
  for (int idx = tid; idx < 2 * POOL_ * H_; idx += 256) {
    int pos = idx >> 5, hh = idx & 31;
    int s = pos < POOL_ ? pos : (S_ - 2 * POOL_) + pos;
    p += bf2f(q[(size_t)s * QKVN + hh * D_ + d]);
  }
#pragma unroll
  for (int m = 1; m < 64; m <<= 1) p += __shfl_xor(p, m);
  __shared__ float red[4];
  if ((tid & 63) == 0) red[tid >> 6] = p;
  __syncthreads();
  if (tid == 0) feat[d] = (red[0] + red[1] + red[2] + red[3]) * (1.f / (2 * POOL_ * H_));
}

// ---------------- router MLP (fp32, single block) ----------------
__global__ void k_router(const float* __restrict__ feat,
                         const float* __restrict__ fe1_w, const float* __restrict__ fe1_b,
                         const float* __restrict__ fe2_w, const float* __restrict__ fe2_b,
                         const float* __restrict__ r1_w, const float* __restrict__ r1_b,
                         const float* __restrict__ r2_w, const float* __restrict__ r2_b,
                         const float* __restrict__ r3_w, const float* __restrict__ r3_b,
                         const float* __restrict__ noise, float* __restrict__ mix) {
  __shared__ float fs[128], h1[1024], h2[256], h3[512], h4[128];
  int tid = threadIdx.x;
  if (tid < 128) fs[tid] = feat[tid];
  __syncthreads();
  for (int o = tid; o < 1024; o += 256) {
    float a = fe1_b[o];
    for (int kk = 0; kk < 128; ++kk) a += fs[kk] * fe1_w[kk * 1024 + o];
    h1[o] = a / (1.f + expf(-a));
  }
  __syncthreads();
  {
    float a = fe2_b[tid];
    for (int kk = 0; kk < 1024; ++kk) a += h1[kk] * fe2_w[kk * 256 + tid];
    h2[tid] = a;
  }
  __syncthreads();
  for (int o = tid; o < 512; o += 256) {
    float a = r1_b[o];
    for (int kk = 0; kk < 256; ++kk) a += h2[kk] * r1_w[kk * 512 + o];
    h3[o] = a / (1.f + expf(-a));
  }
  __syncthreads();
  if (tid < 128) {
    float a = r2_b[tid];
    for (int kk = 0; kk < 512; ++kk) a += h3[kk] * r2_w[kk * 128 + tid];
    h4[tid] = a / (1.f + expf(-a));
  }
  __syncthreads();
  if (tid == 0) {
    float a = r3_b[0];
    for (int kk = 0; kk < 128; ++kk) a += h4[kk] * r3_w[kk];
    float u = noise[0];
    float g = -logf(-logf(u + 1e-8f) + 1e-8f);
    float zs = 1.f / (1.f + expf(-(a + g)));
    mix[0] = zs > 0.5f ? 1.f : 0.f;
  }
}

// ============ deep-pipelined GEMM: BMx256 tile, BK=64, 2 LDS bufs, counted vmcnt ============
// C(M,N) = A(M,K) @ Bt(N,K)^T. 8 waves (2M x 4N). MF = per-wave M-frags (8 -> BM=256, 4 -> BM=128).
// LDS buffer: A BMx64 + B 256x64 bf16 (row = 128 B = 8 x 16B cells).
// Swizzle (both-sides): cell (row, c) holds global chunk c ^ (row&7); frag reads 2-way max (free).
// Staging unit = 1 glds16/thread (8 KB). A units = MF/2, B units = 4.
// Schedule/K-tile: [boundary: bar(1); issue u0,u1(t+2); vmcnt(2); bar(2)]
//                  [ph1: issue u2,u3(t+1); 12 ds_read; setprio(1); 32 MFMA khalf0]
//                  [ph2: issue u4,u5(t+1); ds_read; setprio(1); 32 MFMA khalf1]
//                  [issue u6..(t+1)]
// vmcnt never drains to 0 in the main loop (T4); setprio = T5.
template <int MF>
__device__ __forceinline__ void stage_u(const u16* __restrict__ A, const u16* __restrict__ Bt,
                                        u16* buf, int m0, int n0, int K, int k0, int unit, int tid) {
  constexpr int AU = MF / 2;
  if (unit < AU) {
    int cell = unit * 512 + tid;
    int row = cell >> 3, c = cell & 7;
    glds16(A + (size_t)(m0 + row) * K + k0 + ((c ^ (row & 7)) * 8),
           buf + ((size_t)(unit * 512 + (tid & ~63))) * 8);
  } else {
    int cell = (unit - AU) * 512 + tid;
    int row = cell >> 3, c = cell & 7;
    glds16(Bt + (size_t)(n0 + row) * K + k0 + ((c ^ (row & 7)) * 8),
           buf + (size_t)MF * 2048 + ((size_t)((unit - AU) * 512 + (tid & ~63))) * 8);
  }
}

template <int MF, int OUTF32>
__global__ __launch_bounds__(512, 2) void gemm_dp(const u16* __restrict__ A, const u16* __restrict__ Bt,
                                                  void* __restrict__ C, int M, int N, int K, int NTN) {
  constexpr int BM = MF * 32;
  constexpr int U = MF / 2 + 4;
  constexpr int TE = (BM + 256) * 64;  // u16 per buffer
  __shared__ __align__(16) u16 lds[2 * TE];
  const int tid = threadIdx.x, w = tid >> 6, ln = tid & 63;
  const int lr = ln & 15, lk = ln >> 4;
  const int wr = w >> 2, wc = w & 3;
  // bijective XCD swizzle (grids here are multiples of 8)
  const int nwg = gridDim.x, cpx = nwg >> 3;
  const int wg = (blockIdx.x & 7) * cpx + (blockIdx.x >> 3);
  const int m0 = (wg / NTN) * BM, n0 = (wg % NTN) * 256;
  f32x4 acc[MF][4];
#pragma unroll
  for (int i = 0; i < MF; ++i)
#pragma unroll
    for (int j = 0; j < 4; ++j) acc[i][j] = (f32x4){0.f, 0.f, 0.f, 0.f};
  const int nt = K / 64;
  // prologue: tile 0 fully + units 0,1 of tile 1
#pragma unroll
  for (int i = 0; i < U; ++i) stage_u<MF>(A, Bt, lds, m0, n0, K, 0, i, tid);
  stage_u<MF>(A, Bt, lds + TE, m0, n0, K, 64, 0, tid);
  stage_u<MF>(A, Bt, lds + TE, m0, n0, K, 64, 1, tid);
  asm volatile("s_waitcnt vmcnt(2)" ::: "memory");
  asm volatile("s_barrier" ::: "memory");
  for (int t = 0; t < nt; ++t) {
    const u16* cb = lds + (t & 1) * TE;
    u16* nb = lds + ((t + 1) & 1) * TE;
    const bool hn = (t + 1 < nt);
    const int kn = (t + 1) * 64;
    auto compute_half = [&](int kh) {
      bf16x8 af[MF], bfr[4];
#pragma unroll
      for (int mf = 0; mf < MF; ++mf) {
        int row = wr * (MF * 16) + mf * 16 + lr;
        af[mf] = *(const bf16x8*)&cb[row * 64 + (((kh * 4 + lk) ^ (row & 7)) * 8)];
      }
#pragma unroll
      for (int nf = 0; nf < 4; ++nf) {
        int brow = wc * 64 + nf * 16 + lr;
        bfr[nf] = *(const bf16x8*)&cb[BM * 64 + brow * 64 + (((kh * 4 + lk) ^ (brow & 7)) * 8)];
      }
      __builtin_amdgcn_s_setprio(1);
#pragma unroll
      for (int mf = 0; mf < MF; ++mf)
#pragma unroll
        for (int nf = 0; nf < 4; ++nf)
          acc[mf][nf] = __builtin_amdgcn_mfma_f32_16x16x32_bf16(af[mf], bfr[nf], acc[mf][nf], 0, 0, 0);
      __builtin_amdgcn_s_setprio(0);
    };
    if (hn) { stage_u<MF>(A, Bt, nb, m0, n0, K, kn, 2, tid); stage_u<MF>(A, Bt, nb, m0, n0, K, kn, 3, tid); }
    __builtin_amdgcn_sched_barrier(0);
    compute_half(0);
    if (hn) { stage_u<MF>(A, Bt, nb, m0, n0, K, kn, 4, tid); stage_u<MF>(A, Bt, nb, m0, n0, K, kn, 5, tid); }
    __builtin_amdgcn_sched_barrier(0);
    compute_half(1);
    if (hn) {
#pragma unroll
      for (int i = 6; i < U; ++i) stage_u<MF>(A, Bt, nb, m0, n0, K, kn, i, tid);
      asm volatile("s_barrier" ::: "memory");            // (1) all reads of cb done
      if (t + 2 < nt) {
        stage_u<MF>(A, Bt, (u16*)cb, m0, n0, K, (t + 2) * 64, 0, tid);
        stage_u<MF>(A, Bt, (u16*)cb, m0, n0, K, (t + 2) * 64, 1, tid);
        asm volatile("s_waitcnt vmcnt(2)" ::: "memory"); // t+1 resident (own); keep t+2's 2 in flight
      } else {
        asm volatile("s_waitcnt vmcnt(0)" ::: "memory"); // final drain
      }
      asm volatile("s_barrier" ::: "memory");            // (2) t+1 resident (all waves)
    }
  }
  // epilogue
#pragma unroll
  for (int mf = 0; mf < MF; ++mf) {
    int row = m0 + wr * (MF * 16) + mf * 16 + lk * 4;
#pragma unroll
    for (int nf = 0; nf < 4; ++nf) {
      int col = n0 + wc * 64 + nf * 16 + lr;
#pragma unroll
      for (int jj = 0; jj < 4; ++jj) {
        float v = acc[mf][nf][jj];
        if (OUTF32) ((float*)C)[(size_t)(row + jj) * N + col] = v;
        else ((u16*)C)[(size_t)(row + jj) * N + col] = f2bf(v);
      }
    }
  }
}

// ---------------- fused attention: 64 q-rows/block, KVB=64, XOR-swizzled LDS ----------------
__global__ __launch_bounds__(256) void k_attn(const u16* __restrict__ q, const u16* __restrict__ kr,
                                              const u16* __restrict__ vt, u16* __restrict__ o,
                                              const float* __restrict__ mixp, int qs) {
  __shared__ __align__(16) u16 Ks[KVB * 128];      // (kpos, d) swizzled
  __shared__ __align__(16) u16 Vs[128 * KVB];      // (d, kpos) swizzled
  __shared__ __align__(16) u16 Ps[4][16 * KVB];    // per-wave (q, kpos) swizzled
  const int tid = threadIdx.x, w = tid >> 6, ln = tid & 63;
  const int lr = ln & 15, lk = ln >> 4;
  const int bid = blockIdx.x;
  const int qblk = (S_ / 64 - 1) - (bid >> 5);     // longest blocks dispatch first
  const int h = bid & 31, kv = h >> 2;
  const bool strm = (*mixp) > 0.5f;
  const int q0 = qblk * 64;
  const int qrow = q0 + w * 16 + lr;
  bf16x8 qf[4];
#pragma unroll
  for (int c = 0; c < 4; ++c)
    qf[c] = *(const bf16x8*)(q + (size_t)qrow * qs + h * D_ + c * 32 + lk * 8);
  f32x4 oacc[8];
#pragma unroll
  for (int c = 0; c < 8; ++c) oacc[c] = (f32x4){0.f, 0.f, 0.f, 0.f};
  float mrun[4], lrun[4];
#pragma unroll
  for (int j = 0; j < 4; ++j) { mrun[j] = -1e30f; lrun[j] = 0.f; }
  const u16* kbase = kr + (size_t)kv * S_ * D_;
  const u16* vbase = vt + (size_t)kv * D_ * S_;
  const int qg0 = q0 + w * 16 + lk * 4;
  const float scale = 0.08838834764831845f;
  const int ntiles = qblk + 1;
  for (int kt = 0; kt < ntiles; ++kt) {
    const int kb0 = kt * KVB;
    if (strm && kb0 >= SINK_ && kb0 + KVB - 1 + WIN_ <= q0) continue;
    __syncthreads();
#pragma unroll
    for (int c = 0; c < 4; ++c) {
      int r0 = c * 16 + w * 4;
      int rg = r0 + (ln >> 4);
      int cg = (ln & 15) ^ (rg & 7);
      glds16(kbase + (size_t)(kb0 + rg) * D_ + cg * 8, &Ks[r0 * 128]);
    }
#pragma unroll
    for (int c = 0; c < 4; ++c) {
      int r0 = c * 32 + w * 8;
      int rg = r0 + (ln >> 3);
      int cg = (ln & 7) ^ (rg & 7);
      glds16(vbase + (size_t)rg * S_ + kb0 + cg * 8, &Vs[r0 * KVB]);
    }
    __syncthreads();
    f32x4 sg[4];
#pragma unroll
    for (int g = 0; g < 4; ++g) sg[g] = (f32x4){0.f, 0.f, 0.f, 0.f};
    __builtin_amdgcn_s_setprio(1);
#pragma unroll
    for (int g = 0; g < 4; ++g) {
      int krow = g * 16 + lr;
      int sw = krow & 7;
#pragma unroll
      for (int c = 0; c < 4; ++c) {
        bf16x8 kf = *(const bf16x8*)&Ks[krow * 128 + (((c * 4 + lk) ^ sw) * 8)];
        sg[g] = __builtin_amdgcn_mfma_f32_16x16x32_bf16(qf[c], kf, sg[g], 0, 0, 0);
      }
    }
    __builtin_amdgcn_s_setprio(0);
    const bool lastt = (kt == qblk);
    const bool needm = lastt ||
        (strm && !(kb0 + KVB <= SINK_ || kb0 >= q0 + 64 - WIN_));
    if (needm) {
#pragma unroll
      for (int g = 0; g < 4; ++g) {
        int kg = kb0 + g * 16 + lr;
#pragma unroll
        for (int j = 0; j < 4; ++j) {
          int qi = qg0 + j;
          float v = sg[g][j] * scale;
          bool ok = (kg <= qi) && (!strm || kg < SINK_ || kg > qi - WIN_);
          sg[g][j] = ok ? v : -1e30f;
        }
      }
    } else {
#pragma unroll
      for (int g = 0; g < 4; ++g)
#pragma unroll
        for (int j = 0; j < 4; ++j) sg[g][j] *= scale;
    }
    float rmax[4];
#pragma unroll
    for (int j = 0; j < 4; ++j)
      rmax[j] = fmaxf(fmaxf(sg[0][j], sg[1][j]), fmaxf(sg[2][j], sg[3][j]));
#pragma unroll
    for (int m2 = 1; m2 < 16; m2 <<= 1)
#pragma unroll
      for (int j = 0; j < 4; ++j) rmax[j] = fmaxf(rmax[j], __shfl_xor(rmax[j], m2));
    // T13 defer-max: skip rescale when per-tile max growth <= 8 (P bounded by e^8)
    float dmax = rmax[0] - mrun[0];
#pragma unroll
    for (int j = 1; j < 4; ++j) dmax = fmaxf(dmax, rmax[j] - mrun[j]);
    if (!__all(dmax <= 8.f)) {
      float corr[4];
#pragma unroll
      for (int j = 0; j < 4; ++j) {
        float mn = fmaxf(mrun[j], rmax[j]);
        corr[j] = __expf(mrun[j] - mn);
        mrun[j] = mn;
        lrun[j] *= corr[j];
      }
#pragma unroll
      for (int c = 0; c < 8; ++c) {
        f32x4 t = oacc[c];
        t[0] *= corr[0]; t[1] *= corr[1]; t[2] *= corr[2]; t[3] *= corr[3];
        oacc[c] = t;
      }
    }
    float rsum[4] = {0.f, 0.f, 0.f, 0.f};
#pragma unroll
    for (int g = 0; g < 4; ++g)
#pragma unroll
      for (int j = 0; j < 4; ++j) {
        float p = __expf(sg[g][j] - mrun[j]);
        sg[g][j] = p;
        rsum[j] += p;
      }
#pragma unroll
    for (int m2 = 1; m2 < 16; m2 <<= 1)
#pragma unroll
      for (int j = 0; j < 4; ++j) rsum[j] += __shfl_xor(rsum[j], m2);
#pragma unroll
    for (int j = 0; j < 4; ++j) lrun[j] += rsum[j];
#pragma unroll
    for (int g = 0; g < 4; ++g) {
      int col = g * 16 + lr;
      int c16 = col >> 3;
#pragma unroll
      for (int j = 0; j < 4; ++j) {
        int row = lk * 4 + j;
        Ps[w][row * KVB + ((c16 ^ (row & 7)) * 8) + (col & 7)] = f2bf(sg[g][j]);
      }
    }
    __builtin_amdgcn_s_setprio(1);
#pragma unroll
    for (int half = 0; half < 2; ++half) {
      bf16x8 pf = *(const bf16x8*)&Ps[w][lr * KVB + (((half * 4 + lk) ^ (lr & 7)) * 8)];
#pragma unroll
      for (int cc = 0; cc < 8; ++cc) {
        int vrow = cc * 16 + lr;
        bf16x8 vf = *(const bf16x8*)&Vs[vrow * KVB + (((half * 4 + lk) ^ (vrow & 7)) * 8)];
        oacc[cc] = __builtin_amdgcn_mfma_f32_16x16x32_bf16(pf, vf, oacc[cc], 0, 0, 0);
      }
    }
    __builtin_amdgcn_s_setprio(0);
  }
#pragma unroll
  for (int cc = 0; cc < 8; ++cc)
#pragma unroll
    for (int j = 0; j < 4; ++j) {
      float ov = oacc[cc][j] / lrun[j];
      o[(size_t)(qg0 + j) * HID_ + h * D_ + cc * 16 + lr] = f2bf(ov);
    }
}

extern "C" void kernel_launch(void* const* d_in, const int* in_sizes, int n_in,
                              void* d_out, int out_size, void* d_ws, size_t ws_size,
                              hipStream_t stream) {
  const float* hs = (const float*)d_in[0];
  const float* Wq = (const float*)d_in[1];
  const float* Wk = (const float*)d_in[2];
  const float* Wv = (const float*)d_in[3];
  const float* Wo = (const float*)d_in[4];
  const float* fe1_w = (const float*)d_in[5];
  const float* fe1_b = (const float*)d_in[6];
  const float* fe2_w = (const float*)d_in[7];
  const float* fe2_b = (const float*)d_in[8];
  const float* r1_w = (const float*)d_in[9];
  const float* r1_b = (const float*)d_in[10];
  const float* r2_w = (const float*)d_in[11];
  const float* r2_b = (const float*)d_in[12];
  const float* r3_w = (const float*)d_in[13];
  const float* r3_b = (const float*)d_in[14];
  const float* noise = (const float*)d_in[15];

  char* ws = (char*)d_ws;
  size_t off = 0;
  auto alloc = [&](size_t b) { char* p = ws + off; off += (b + 255) & ~(size_t)255; return p; };
  u16* hsb = (u16*)alloc((size_t)S_ * HID_ * 2);
  u16* wqkv = (u16*)alloc((size_t)QKVN * HID_ * 2);  // [Wq^T; Wk^T; Wv^T]; later reused for Wo^T
  u16* qkvbuf = (u16*)alloc((size_t)S_ * QKVN * 2);  // cols: 0..4095 q | 4096..5119 k | 5120..6143 v
  u16* krbuf = (u16*)alloc((size_t)S_ * KVD_ * 2);
  u16* vtbuf = (u16*)alloc((size_t)S_ * KVD_ * 2);
  u16* obuf = (u16*)alloc((size_t)S_ * HID_ * 2);
  float* cosT = (float*)alloc((size_t)S_ * 64 * 4);
  float* sinT = (float*)alloc((size_t)S_ * 64 * 4);
  float* feat = (float*)alloc(512);
  float* mix = (float*)alloc(256);

  k_f32_to_bf16<<<dim3(S_ * HID_ / 4 / 256), dim3(256), 0, stream>>>(hs, hsb, S_ * HID_ / 4);
  k_transpose_w<<<dim3(HID_ / 32, HID_ / 32), dim3(256), 0, stream>>>(Wq, wqkv, HID_, HID_);
  k_transpose_w<<<dim3(KVD_ / 32, HID_ / 32), dim3(256), 0, stream>>>(Wk, wqkv + (size_t)4096 * HID_, HID_, KVD_);
  k_transpose_w<<<dim3(KVD_ / 32, HID_ / 32), dim3(256), 0, stream>>>(Wv, wqkv + (size_t)5120 * HID_, HID_, KVD_);
  k_rope_table<<<dim3(S_ * 64 / 256), dim3(256), 0, stream>>>(cosT, sinT);

  // fused QKV GEMM: M=2048 (8 tiles of 256), N=6144 (24 tiles) -> 192 blocks, 1/CU
  gemm_dp<8, 0><<<dim3((S_ / 256) * (QKVN / 256)), dim3(512), 0, stream>>>(hsb, wqkv, (void*)qkvbuf,
                                                                           S_, QKVN, HID_, QKVN / 256);

  k_rope_q<<<dim3(S_ * H_ * 64 / 256), dim3(256), 0, stream>>>(qkvbuf, cosT, sinT);
  k_rope_k<<<dim3(S_ * KV_ * 64 / 256), dim3(256), 0, stream>>>(qkvbuf, krbuf, cosT, sinT);
  k_transpose_v<<<dim3(S_ / 32, D_ / 32, KV_), dim3(256), 0, stream>>>(qkvbuf, vtbuf);

  k_feat<<<dim3(D_), dim3(256), 0, stream>>>(qkvbuf, feat);
  k_router<<<dim3(1), dim3(256), 0, stream>>>(feat, fe1_w, fe1_b, fe2_w, fe2_b,
                                              r1_w, r1_b, r2_w, r2_b, r3_w, r3_b, noise, mix);

  k_attn<<<dim3((S_ / 64) * H_), dim3(256), 0, stream>>>(qkvbuf, krbuf, vtbuf, obuf, mix, QKVN);

  // Wo^T reuses the wqkv slot (QKV GEMM complete by stream order)
  k_transpose_w<<<dim3(HID_ / 32, HID_ / 32), dim3(256), 0, stream>>>(Wo, wqkv, HID_, HID_);
  // Wo GEMM: M=2048 (16 tiles of 128), N=4096 (16 tiles) -> 256 blocks = full CU coverage
  gemm_dp<4, 1><<<dim3((S_ / 128) * (HID_ / 256)), dim3(512), 0, stream>>>(obuf, wqkv, d_out,
                                                                           S_, HID_, HID_, HID_ / 256);
}